// Round 1
// baseline (16648.253 us; speedup 1.0000x reference)
//
#include <hip/hip_runtime.h>

typedef unsigned short u16;
typedef __bf16 bf16x8 __attribute__((ext_vector_type(8)));
typedef float f32x4 __attribute__((ext_vector_type(4)));

#define D_    768
#define DM_   3072
#define NL_   12
#define NT_   577
#define NP_   576
#define B_    64
#define MREAL (B_*NT_)      /* 36928 */
#define MPAD  36992         /* 289*128 */
#define NC_   1000
#define IMG_  384

__device__ __forceinline__ float bf2f(u16 v){
  union { unsigned u; float f; } c; c.u = ((unsigned)v) << 16; return c.f;
}
__device__ __forceinline__ u16 f2bf(float f){
  union { float f; unsigned u; } c; c.f = f;
  unsigned r = c.u + 0x7FFFu + ((c.u >> 16) & 1u);
  return (u16)(r >> 16);
}
__device__ __forceinline__ float gelu_f(float x){
  return 0.5f * x * (1.0f + erff(x * 0.70710678118654752f));
}
__device__ __forceinline__ void gload16(const void* g, void* l){
  __builtin_amdgcn_global_load_lds((const __attribute__((address_space(1))) void*)g,
                                   (__attribute__((address_space(3))) void*)l, 16, 0, 0);
}

// ---------------------------------------------------------------------------
// GEMM: C[M,N] = A[M,K] (bf16, row-major) x Bt[N,K] (bf16, N-major = B^T)
// 128x128 tile, BK=32, 4 waves 2x2, 16x16x32 MFMA, 4x4 acc per wave.
// EPI: 0=bf16 bias, 1=f32 bias+res, 2=bf16 gelu(bias), 3=f32 gelu(bias)+res,
//      4=f32 bias, 5=f32 gelu(bias) bounded store [Ms,Ns]
// ---------------------------------------------------------------------------
template<int EPI>
__global__ __launch_bounds__(256) void gemm_k(
    const u16* __restrict__ A, const u16* __restrict__ Bt,
    const float* __restrict__ bias, const float* __restrict__ res,
    void* __restrict__ outv, int K, int ldo, int Ms, int Ns)
{
  __shared__ u16 As[128*32];
  __shared__ u16 Bs[128*32];
  const int tid = threadIdx.x;
  const int l   = tid & 63;
  const int w   = tid >> 6;
  const int wm  = w >> 1, wn = w & 1;
  const int bm  = blockIdx.y, bn = blockIdx.x;
  const int lrow = l & 15;
  const int lk   = (l >> 4) * 8;

  const int c0 = tid, c1 = tid + 256;
  const size_t abase = (size_t)bm * 128 * K;
  const size_t bbase = (size_t)bn * 128 * K;
  const size_t a0 = abase + (size_t)(c0 >> 2) * K + (c0 & 3) * 8;
  const size_t a1 = abase + (size_t)(c1 >> 2) * K + (c1 & 3) * 8;
  const size_t b0 = bbase + (size_t)(c0 >> 2) * K + (c0 & 3) * 8;
  const size_t b1 = bbase + (size_t)(c1 >> 2) * K + (c1 & 3) * 8;

  f32x4 acc[4][4];
  #pragma unroll
  for (int i = 0; i < 4; i++)
    #pragma unroll
    for (int j = 0; j < 4; j++) acc[i][j] = {0.f, 0.f, 0.f, 0.f};

  const int nk = K >> 5;
  for (int kt = 0; kt < nk; ++kt) {
    const int koff = kt * 32;
    gload16(A  + a0 + koff, As + c0 * 8);
    gload16(A  + a1 + koff, As + c1 * 8);
    gload16(Bt + b0 + koff, Bs + c0 * 8);
    gload16(Bt + b1 + koff, Bs + c1 * 8);
    __syncthreads();
    bf16x8 af[4], bfr[4];
    #pragma unroll
    for (int mi = 0; mi < 4; mi++)
      af[mi] = *(const bf16x8*)(As + (wm*64 + mi*16 + lrow)*32 + lk);
    #pragma unroll
    for (int ni = 0; ni < 4; ni++)
      bfr[ni] = *(const bf16x8*)(Bs + (wn*64 + ni*16 + lrow)*32 + lk);
    #pragma unroll
    for (int mi = 0; mi < 4; mi++)
      #pragma unroll
      for (int ni = 0; ni < 4; ni++)
        acc[mi][ni] = __builtin_amdgcn_mfma_f32_16x16x32_bf16(af[mi], bfr[ni], acc[mi][ni], 0, 0, 0);
    __syncthreads();
  }

  const int orow0 = bm*128 + wm*64;
  const int ocol0 = bn*128 + wn*64;
  #pragma unroll
  for (int mi = 0; mi < 4; mi++) {
    #pragma unroll
    for (int ni = 0; ni < 4; ni++) {
      #pragma unroll
      for (int r = 0; r < 4; r++) {
        const int row = orow0 + mi*16 + (l >> 4)*4 + r;
        const int col = ocol0 + ni*16 + (l & 15);
        float bv;
        if constexpr (EPI == 5) bv = (col < Ns) ? bias[col] : 0.f;
        else bv = bias[col];
        const float v = acc[mi][ni][r] + bv;
        const size_t idx = (size_t)row * ldo + col;
        if constexpr (EPI == 0) ((u16*)outv)[idx] = f2bf(v);
        else if constexpr (EPI == 1) ((float*)outv)[idx] = v + res[idx];
        else if constexpr (EPI == 2) ((u16*)outv)[idx] = f2bf(gelu_f(v));
        else if constexpr (EPI == 3) ((float*)outv)[idx] = gelu_f(v) + res[idx];
        else if constexpr (EPI == 4) ((float*)outv)[idx] = v;
        else if constexpr (EPI == 5) {
          if (row < Ms && col < Ns) ((float*)outv)[(size_t)row * Ns + col] = gelu_f(v);
        }
      }
    }
  }
}

// ---------------------------------------------------------------------------
// Weight convert+transpose: W[K,N] f32 -> Wt[Npad,K] bf16 (zero-pad rows>=N)
// block (32,8), grid (Npad/32, K/32)
// ---------------------------------------------------------------------------
__global__ void wconv_k(const float* __restrict__ W, u16* __restrict__ Wt,
                        int K, int N)
{
  __shared__ float tile[32][33];
  const int n0 = blockIdx.x * 32, k0 = blockIdx.y * 32;
  const int tx = threadIdx.x, ty = threadIdx.y;
  #pragma unroll
  for (int r = 0; r < 4; r++) {
    const int kk = k0 + ty + r*8;
    const int nn = n0 + tx;
    tile[ty + r*8][tx] = (nn < N) ? W[(size_t)kk * N + nn] : 0.f;
  }
  __syncthreads();
  #pragma unroll
  for (int r = 0; r < 4; r++) {
    const int nn = n0 + ty + r*8;
    Wt[(size_t)nn * K + k0 + tx] = f2bf(tile[tx][ty + r*8]);
  }
}

// ---------------------------------------------------------------------------
// Patchify: x (B,3,384,384) f32 -> hb rows (b*577+1+p) bf16, j = c*256+ph*16+pw
// ---------------------------------------------------------------------------
__global__ void patchify_k(const float* __restrict__ x, u16* __restrict__ hb)
{
  const int blk = blockIdx.x;
  const int b = blk / NP_, p = blk % NP_;
  const int pr = p / 24, pc = p % 24;
  const size_t row = (size_t)b * NT_ + 1 + p;
  #pragma unroll
  for (int u = 0; u < 3; u++) {
    const int j  = threadIdx.x + u * 256;
    const int c  = j >> 8, ph = (j >> 4) & 15, pw = j & 15;
    const float v = x[((size_t)(b*3 + c) * IMG_ + pr*16 + ph) * IMG_ + pc*16 + pw];
    hb[row * D_ + j] = f2bf(v);
  }
}

// z fixup: cls rows = ce+pe[0] (overwrite), others += pe[t]
__global__ void posecls_k(float* __restrict__ z, const float* __restrict__ ce,
                          const float* __restrict__ pe)
{
  const int row = blockIdx.x;
  const int t = row % NT_;
  const size_t base = (size_t)row * D_;
  #pragma unroll
  for (int u = 0; u < 3; u++) {
    const int j = threadIdx.x + u * 256;
    if (t == 0) z[base + j] = ce[j] + pe[j];
    else        z[base + j] += pe[(size_t)t * D_ + j];
  }
}

// LayerNorm: one wave per row (768 = 12 x 64), f32 in -> bf16 out
__global__ void ln_k(const float* __restrict__ z, const float* __restrict__ w,
                     const float* __restrict__ b, u16* __restrict__ out)
{
  const int row = blockIdx.x * 4 + (threadIdx.x >> 6);
  const int l = threadIdx.x & 63;
  const float* zr = z + (size_t)row * D_;
  float xv[12];
  float s = 0.f;
  #pragma unroll
  for (int j = 0; j < 12; j++) { xv[j] = zr[j*64 + l]; s += xv[j]; }
  #pragma unroll
  for (int m = 1; m < 64; m <<= 1) s += __shfl_xor(s, m, 64);
  const float mean = s * (1.0f / 768.0f);
  float ss = 0.f;
  #pragma unroll
  for (int j = 0; j < 12; j++) { const float d = xv[j] - mean; ss += d * d; }
  #pragma unroll
  for (int m = 1; m < 64; m <<= 1) ss += __shfl_xor(ss, m, 64);
  const float rinv = rsqrtf(ss * (1.0f / 768.0f) + 1e-5f);
  const size_t ob = (size_t)row * D_;
  #pragma unroll
  for (int j = 0; j < 12; j++) {
    const int cidx = j*64 + l;
    out[ob + cidx] = f2bf((xv[j] - mean) * rinv * w[cidx] + b[cidx]);
  }
}

// Final LN over cls rows -> yb[128][768] bf16 (rows >= 64 zeroed)
__global__ void lncls_k(const float* __restrict__ z, const float* __restrict__ w,
                        const float* __restrict__ b, u16* __restrict__ out)
{
  const int row = blockIdx.x * 4 + (threadIdx.x >> 6);   // 0..127
  const int l = threadIdx.x & 63;
  const size_t ob = (size_t)row * D_;
  if (row >= B_) {
    #pragma unroll
    for (int j = 0; j < 12; j++) out[ob + j*64 + l] = 0;
    return;
  }
  const float* zr = z + (size_t)row * NT_ * D_;
  float xv[12];
  float s = 0.f;
  #pragma unroll
  for (int j = 0; j < 12; j++) { xv[j] = zr[j*64 + l]; s += xv[j]; }
  #pragma unroll
  for (int m = 1; m < 64; m <<= 1) s += __shfl_xor(s, m, 64);
  const float mean = s * (1.0f / 768.0f);
  float ss = 0.f;
  #pragma unroll
  for (int j = 0; j < 12; j++) { const float d = xv[j] - mean; ss += d * d; }
  #pragma unroll
  for (int m = 1; m < 64; m <<= 1) ss += __shfl_xor(ss, m, 64);
  const float rinv = rsqrtf(ss * (1.0f / 768.0f) + 1e-5f);
  #pragma unroll
  for (int j = 0; j < 12; j++) {
    const int cidx = j*64 + l;
    out[ob + cidx] = f2bf((xv[j] - mean) * rinv * w[cidx] + b[cidx]);
  }
}

// Per-token head-axis attention: qkv row (2304 bf16) -> o row (768 bf16)
// One wave per token, lane = d (0..63), 12x12 softmax via shuffle reduce.
__global__ void attn_k(const u16* __restrict__ qkv, u16* __restrict__ o)
{
  const int row = blockIdx.x * 4 + (threadIdx.x >> 6);
  const int l = threadIdx.x & 63;
  const u16* base = qkv + (size_t)row * (3 * D_);
  float q[12], k[12], v[12];
  #pragma unroll
  for (int h = 0; h < 12; h++) {
    q[h] = bf2f(base[h*64 + l]);
    k[h] = bf2f(base[D_ + h*64 + l]);
    v[h] = bf2f(base[2*D_ + h*64 + l]);
  }
  const size_t ob = (size_t)row * D_;
  #pragma unroll
  for (int i = 0; i < 12; i++) {
    float s[12];
    #pragma unroll
    for (int j = 0; j < 12; j++) s[j] = q[i] * k[j];
    #pragma unroll
    for (int m = 1; m < 64; m <<= 1) {
      #pragma unroll
      for (int j = 0; j < 12; j++) s[j] += __shfl_xor(s[j], m, 64);
    }
    float mx = s[0];
    #pragma unroll
    for (int j = 1; j < 12; j++) mx = fmaxf(mx, s[j]);
    float den = 0.f, acc = 0.f;
    #pragma unroll
    for (int j = 0; j < 12; j++) {
      const float p = __expf((s[j] - mx) * 0.125f);
      den += p; acc += p * v[j];
    }
    o[ob + i*64 + l] = f2bf(acc / den);
  }
}

// ---------------------------------------------------------------------------
extern "C" void kernel_launch(void* const* d_in, const int* in_sizes, int n_in,
                              void* d_out, int out_size, void* d_ws, size_t ws_size,
                              hipStream_t stream)
{
  const float* x    = (const float*)d_in[0];
  const float* ce   = (const float*)d_in[1];
  const float* pe   = (const float*)d_in[2];
  const float* pw   = (const float*)d_in[3];
  const float* pb   = (const float*)d_in[4];
  const float* qkvw = (const float*)d_in[5];
  const float* qkvb = (const float*)d_in[6];
  const float* topw = (const float*)d_in[7];
  const float* topb = (const float*)d_in[8];
  const float* l1w  = (const float*)d_in[9];
  const float* l1b  = (const float*)d_in[10];
  const float* l2w  = (const float*)d_in[11];
  const float* l2b  = (const float*)d_in[12];
  const float* w1   = (const float*)d_in[13];
  const float* b1   = (const float*)d_in[14];
  const float* w2   = (const float*)d_in[15];
  const float* b2   = (const float*)d_in[16];
  const float* l3w  = (const float*)d_in[17];
  const float* l3b  = (const float*)d_in[18];
  const float* hw1  = (const float*)d_in[19];
  const float* hb1  = (const float*)d_in[20];
  const float* hw2  = (const float*)d_in[21];
  const float* hb2  = (const float*)d_in[22];

  char* ws = (char*)d_ws;
  constexpr size_t SZ_Z  = (size_t)MPAD * D_ * 4;
  constexpr size_t SZ_HB = (size_t)MPAD * D_ * 2;
  constexpr size_t SZ_QM = (size_t)MPAD * DM_ * 2;
  constexpr size_t SZ_WB = (size_t)DM_ * 1024 * 2;
  constexpr size_t SZ_YB = (size_t)128 * D_ * 2;
  float* z  = (float*)ws;
  u16*   hb = (u16*)(ws + SZ_Z);
  u16*   qm = (u16*)(ws + SZ_Z + SZ_HB);
  u16*   wb = (u16*)(ws + SZ_Z + SZ_HB + SZ_QM);
  u16*   yb = (u16*)(ws + SZ_Z + SZ_HB + SZ_QM + SZ_WB);
  u16*   t1 = (u16*)(ws + SZ_Z + SZ_HB + SZ_QM + SZ_WB + SZ_YB);

  const dim3 blk(256);
  const dim3 wblk(32, 8);
  const int MT = MPAD / 128;   // 289

  // Patch embedding
  patchify_k<<<B_ * NP_, blk, 0, stream>>>(x, hb);
  wconv_k<<<dim3(D_/32, D_/32), wblk, 0, stream>>>(pw, wb, D_, D_);
  gemm_k<4><<<dim3(D_/128, MT), blk, 0, stream>>>(hb, wb, pb, nullptr, z, D_, D_, 0, 0);
  posecls_k<<<MREAL, blk, 0, stream>>>(z, ce, pe);

  for (int i = 0; i < NL_; i++) {
    ln_k<<<MPAD/4, blk, 0, stream>>>(z, l1w + i*D_, l1b + i*D_, hb);
    wconv_k<<<dim3(3*D_/32, D_/32), wblk, 0, stream>>>(qkvw + (size_t)i*D_*3*D_, wb, D_, 3*D_);
    gemm_k<0><<<dim3(3*D_/128, MT), blk, 0, stream>>>(hb, wb, qkvb + i*3*D_, nullptr, qm, D_, 3*D_, 0, 0);
    attn_k<<<MREAL/4, blk, 0, stream>>>(qm, hb);
    wconv_k<<<dim3(D_/32, D_/32), wblk, 0, stream>>>(topw + (size_t)i*D_*D_, wb, D_, D_);
    gemm_k<1><<<dim3(D_/128, MT), blk, 0, stream>>>(hb, wb, topb + i*D_, z, z, D_, D_, 0, 0);
    ln_k<<<MPAD/4, blk, 0, stream>>>(z, l2w + i*D_, l2b + i*D_, hb);
    wconv_k<<<dim3(DM_/32, D_/32), wblk, 0, stream>>>(w1 + (size_t)i*D_*DM_, wb, D_, DM_);
    gemm_k<2><<<dim3(DM_/128, MT), blk, 0, stream>>>(hb, wb, b1 + i*DM_, nullptr, qm, D_, DM_, 0, 0);
    wconv_k<<<dim3(D_/32, DM_/32), wblk, 0, stream>>>(w2 + (size_t)i*DM_*D_, wb, DM_, D_);
    gemm_k<3><<<dim3(D_/128, MT), blk, 0, stream>>>(qm, wb, b2 + i*D_, z, z, DM_, D_, 0, 0);
  }

  // Head: LN(cls) -> MLP with gelu after both linears
  lncls_k<<<32, blk, 0, stream>>>(z, l3w, l3b, yb);
  wconv_k<<<dim3(DM_/32, D_/32), wblk, 0, stream>>>(hw1, wb, D_, DM_);
  gemm_k<2><<<dim3(DM_/128, 1), blk, 0, stream>>>(yb, wb, hb1, nullptr, t1, D_, DM_, 0, 0);
  wconv_k<<<dim3(1024/32, DM_/32), wblk, 0, stream>>>(hw2, wb, DM_, NC_);
  gemm_k<5><<<dim3(1024/128, 1), blk, 0, stream>>>(t1, wb, hb2, nullptr, (float*)d_out, DM_, 1024, B_, NC_);
}

// Round 2
// 15807.878 us; speedup vs baseline: 1.0532x; 1.0532x over previous
//
#include <hip/hip_runtime.h>

typedef unsigned short u16;
typedef __bf16 bf16x8 __attribute__((ext_vector_type(8)));
typedef float f32x4 __attribute__((ext_vector_type(4)));

#define D_    768
#define DM_   3072
#define NL_   12
#define NT_   577
#define NP_   576
#define B_    64
#define MREAL (B_*NT_)      /* 36928 */
#define MPAD  36992         /* 289*128 */
#define NC_   1000
#define IMG_  384

__device__ __forceinline__ float bf2f(u16 v){
  union { unsigned u; float f; } c; c.u = ((unsigned)v) << 16; return c.f;
}
__device__ __forceinline__ u16 f2bf(float f){
  union { float f; unsigned u; } c; c.f = f;
  unsigned r = c.u + 0x7FFFu + ((c.u >> 16) & 1u);
  return (u16)(r >> 16);
}
__device__ __forceinline__ float gelu_f(float x){
  return 0.5f * x * (1.0f + erff(x * 0.70710678118654752f));
}
__device__ __forceinline__ void gload16(const void* g, void* l){
  __builtin_amdgcn_global_load_lds((const __attribute__((address_space(1))) void*)g,
                                   (__attribute__((address_space(3))) void*)l, 16, 0, 0);
}

// ---------------------------------------------------------------------------
// GEMM: C[M,N] = A[M,K] (bf16, row-major) x Bt[N,K] (bf16, N-major = B^T)
// 128x128 tile, BK=64, 4 waves 2x2, 16x16x32 MFMA, 4x4 acc per wave.
// LDS tiles [128][64] bf16 with XOR swizzle (col8 ^= row&7), applied on the
// global SOURCE address (global_load_lds writes linearly) and on ds_read.
// 1D grid, bijective XCD swizzle (m204), bn-fastest for A-tile L2 reuse.
// EPI: 0=bf16 bias, 1=f32 bias+res, 2=bf16 gelu(bias), 3=f32 gelu(bias)+res,
//      4=f32 bias, 5=f32 gelu(bias) bounded store [Ms,Ns]
// ---------------------------------------------------------------------------
template<int EPI>
__global__ __launch_bounds__(256) void gemm_k(
    const u16* __restrict__ A, const u16* __restrict__ Bt,
    const float* __restrict__ bias, const float* __restrict__ res,
    void* __restrict__ outv, int K, int ldo, int nbn, int Ms, int Ns)
{
  __shared__ u16 As[128*64];
  __shared__ u16 Bs[128*64];
  const int tid = threadIdx.x;
  const int l   = tid & 63;
  const int w   = tid >> 6;
  const int wm  = w >> 1, wn = w & 1;
  const int lrow = l & 15;

  // ---- bijective XCD swizzle (m204), then bn-fastest decomposition
  const int nwg = gridDim.x;
  const int q = nwg >> 3, r = nwg & 7;
  const int xcd = blockIdx.x & 7, o = blockIdx.x >> 3;
  const int wg = (xcd < r ? xcd * (q + 1) : r * (q + 1) + (xcd - r) * q) + o;
  const int bm = wg / nbn, bn = wg % nbn;

  // ---- staging addresses: thread covers c = tid + 256*i, row=c>>3, col8=c&7
  // source pre-swizzle: col8' = col8 ^ (row&7)  (row&7 == (tid>>3)&7 for all i)
  const int cs8 = ((tid & 7) ^ ((tid >> 3) & 7)) * 8;
  const int rb  = tid >> 3;                       // 0..31
  const size_t abase = (size_t)bm * 128 * K;
  const size_t bbase = (size_t)bn * 128 * K;
  size_t aoff[4], boff[4];
  #pragma unroll
  for (int i = 0; i < 4; i++) {
    aoff[i] = abase + (size_t)(rb + 32 * i) * K + cs8;
    boff[i] = bbase + (size_t)(rb + 32 * i) * K + cs8;
  }

  // ---- fragment read addressing (byte offsets into swizzled LDS)
  const int colA = (l >> 4) << 4;     // 16B slot from k-group
  const int sw   = (lrow & 7) << 4;   // row-XOR term

  f32x4 acc[4][4];
  #pragma unroll
  for (int i = 0; i < 4; i++)
    #pragma unroll
    for (int j = 0; j < 4; j++) acc[i][j] = {0.f, 0.f, 0.f, 0.f};

  const int nk = K >> 6;
  for (int kt = 0; kt < nk; ++kt) {
    const int koff = kt * 64;
    #pragma unroll
    for (int i = 0; i < 4; i++) {
      gload16(A  + aoff[i] + koff, As + tid * 8 + i * 2048);
      gload16(Bt + boff[i] + koff, Bs + tid * 8 + i * 2048);
    }
    __syncthreads();
    #pragma unroll
    for (int kk = 0; kk < 2; kk++) {
      bf16x8 af[4], bfr[4];
      #pragma unroll
      for (int mi = 0; mi < 4; mi++)
        af[mi] = *(const bf16x8*)((const char*)As +
                  ((wm*64 + mi*16 + lrow) << 7) + (((kk << 6) | colA) ^ sw));
      #pragma unroll
      for (int ni = 0; ni < 4; ni++)
        bfr[ni] = *(const bf16x8*)((const char*)Bs +
                  ((wn*64 + ni*16 + lrow) << 7) + (((kk << 6) | colA) ^ sw));
      #pragma unroll
      for (int mi = 0; mi < 4; mi++)
        #pragma unroll
        for (int ni = 0; ni < 4; ni++)
          acc[mi][ni] = __builtin_amdgcn_mfma_f32_16x16x32_bf16(af[mi], bfr[ni], acc[mi][ni], 0, 0, 0);
    }
    __syncthreads();
  }

  const int orow0 = bm*128 + wm*64;
  const int ocol0 = bn*128 + wn*64;
  #pragma unroll
  for (int mi = 0; mi < 4; mi++) {
    #pragma unroll
    for (int ni = 0; ni < 4; ni++) {
      #pragma unroll
      for (int r2 = 0; r2 < 4; r2++) {
        const int row = orow0 + mi*16 + (l >> 4)*4 + r2;
        const int col = ocol0 + ni*16 + (l & 15);
        float bv;
        if constexpr (EPI == 5) bv = (col < Ns) ? bias[col] : 0.f;
        else bv = bias[col];
        const float v = acc[mi][ni][r2] + bv;
        const size_t idx = (size_t)row * ldo + col;
        if constexpr (EPI == 0) ((u16*)outv)[idx] = f2bf(v);
        else if constexpr (EPI == 1) ((float*)outv)[idx] = v + res[idx];
        else if constexpr (EPI == 2) ((u16*)outv)[idx] = f2bf(gelu_f(v));
        else if constexpr (EPI == 3) ((float*)outv)[idx] = gelu_f(v) + res[idx];
        else if constexpr (EPI == 4) ((float*)outv)[idx] = v;
        else if constexpr (EPI == 5) {
          if (row < Ms && col < Ns) ((float*)outv)[(size_t)row * Ns + col] = gelu_f(v);
        }
      }
    }
  }
}

// ---------------------------------------------------------------------------
// Weight convert+transpose: W[K,N] f32 -> Wt[Npad,K] bf16 (zero-pad rows>=N)
// block (32,8), grid (Npad/32, K/32)
// ---------------------------------------------------------------------------
__global__ void wconv_k(const float* __restrict__ W, u16* __restrict__ Wt,
                        int K, int N)
{
  __shared__ float tile[32][33];
  const int n0 = blockIdx.x * 32, k0 = blockIdx.y * 32;
  const int tx = threadIdx.x, ty = threadIdx.y;
  #pragma unroll
  for (int r = 0; r < 4; r++) {
    const int kk = k0 + ty + r*8;
    const int nn = n0 + tx;
    tile[ty + r*8][tx] = (nn < N) ? W[(size_t)kk * N + nn] : 0.f;
  }
  __syncthreads();
  #pragma unroll
  for (int r = 0; r < 4; r++) {
    const int nn = n0 + ty + r*8;
    Wt[(size_t)nn * K + k0 + tx] = f2bf(tile[tx][ty + r*8]);
  }
}

// ---------------------------------------------------------------------------
// Patchify: x (B,3,384,384) f32 -> hb rows (b*577+1+p) bf16, j = c*256+ph*16+pw
// ---------------------------------------------------------------------------
__global__ void patchify_k(const float* __restrict__ x, u16* __restrict__ hb)
{
  const int blk = blockIdx.x;
  const int b = blk / NP_, p = blk % NP_;
  const int pr = p / 24, pc = p % 24;
  const size_t row = (size_t)b * NT_ + 1 + p;
  #pragma unroll
  for (int u = 0; u < 3; u++) {
    const int j  = threadIdx.x + u * 256;
    const int c  = j >> 8, ph = (j >> 4) & 15, pw = j & 15;
    const float v = x[((size_t)(b*3 + c) * IMG_ + pr*16 + ph) * IMG_ + pc*16 + pw];
    hb[row * D_ + j] = f2bf(v);
  }
}

// z fixup: cls rows = ce+pe[0] (overwrite), others += pe[t]
__global__ void posecls_k(float* __restrict__ z, const float* __restrict__ ce,
                          const float* __restrict__ pe)
{
  const int row = blockIdx.x;
  const int t = row % NT_;
  const size_t base = (size_t)row * D_;
  #pragma unroll
  for (int u = 0; u < 3; u++) {
    const int j = threadIdx.x + u * 256;
    if (t == 0) z[base + j] = ce[j] + pe[j];
    else        z[base + j] += pe[(size_t)t * D_ + j];
  }
}

// LayerNorm: one wave per row (768 = 3 x 64 x float4), f32 in -> bf16 out
__global__ void ln_k(const float* __restrict__ z, const float* __restrict__ w,
                     const float* __restrict__ b, u16* __restrict__ out)
{
  const int row = blockIdx.x * 4 + (threadIdx.x >> 6);
  const int l = threadIdx.x & 63;
  const float4* zr = (const float4*)(z + (size_t)row * D_);
  float4 xq[3];
  float s = 0.f;
  #pragma unroll
  for (int j = 0; j < 3; j++) {
    xq[j] = zr[j*64 + l];
    s += xq[j].x + xq[j].y + xq[j].z + xq[j].w;
  }
  #pragma unroll
  for (int m = 1; m < 64; m <<= 1) s += __shfl_xor(s, m, 64);
  const float mean = s * (1.0f / 768.0f);
  float ss = 0.f;
  #pragma unroll
  for (int j = 0; j < 3; j++) {
    const float dx = xq[j].x-mean, dy = xq[j].y-mean, dz = xq[j].z-mean, dw = xq[j].w-mean;
    ss += dx*dx + dy*dy + dz*dz + dw*dw;
  }
  #pragma unroll
  for (int m = 1; m < 64; m <<= 1) ss += __shfl_xor(ss, m, 64);
  const float rinv = rsqrtf(ss * (1.0f / 768.0f) + 1e-5f);
  const size_t ob = (size_t)row * D_;
  #pragma unroll
  for (int j = 0; j < 3; j++) {
    const int c = (j*64 + l) * 4;
    const float4 wv = *(const float4*)(w + c);
    const float4 bv = *(const float4*)(b + c);
    ushort4 ov;
    ov.x = f2bf((xq[j].x - mean) * rinv * wv.x + bv.x);
    ov.y = f2bf((xq[j].y - mean) * rinv * wv.y + bv.y);
    ov.z = f2bf((xq[j].z - mean) * rinv * wv.z + bv.z);
    ov.w = f2bf((xq[j].w - mean) * rinv * wv.w + bv.w);
    *(ushort4*)(out + ob + c) = ov;
  }
}

// Final LN over cls rows -> yb[128][768] bf16 (rows >= 64 zeroed)
__global__ void lncls_k(const float* __restrict__ z, const float* __restrict__ w,
                        const float* __restrict__ b, u16* __restrict__ out)
{
  const int row = blockIdx.x * 4 + (threadIdx.x >> 6);   // 0..127
  const int l = threadIdx.x & 63;
  const size_t ob = (size_t)row * D_;
  if (row >= B_) {
    #pragma unroll
    for (int j = 0; j < 12; j++) out[ob + j*64 + l] = 0;
    return;
  }
  const float* zr = z + (size_t)row * NT_ * D_;
  float xv[12];
  float s = 0.f;
  #pragma unroll
  for (int j = 0; j < 12; j++) { xv[j] = zr[j*64 + l]; s += xv[j]; }
  #pragma unroll
  for (int m = 1; m < 64; m <<= 1) s += __shfl_xor(s, m, 64);
  const float mean = s * (1.0f / 768.0f);
  float ss = 0.f;
  #pragma unroll
  for (int j = 0; j < 12; j++) { const float d = xv[j] - mean; ss += d * d; }
  #pragma unroll
  for (int m = 1; m < 64; m <<= 1) ss += __shfl_xor(ss, m, 64);
  const float rinv = rsqrtf(ss * (1.0f / 768.0f) + 1e-5f);
  #pragma unroll
  for (int j = 0; j < 12; j++) {
    const int cidx = j*64 + l;
    out[ob + cidx] = f2bf((xv[j] - mean) * rinv * w[cidx] + b[cidx]);
  }
}

// Per-token head-axis attention: qkv row (2304 bf16) -> o row (768 bf16)
__global__ void attn_k(const u16* __restrict__ qkv, u16* __restrict__ o)
{
  const int row = blockIdx.x * 4 + (threadIdx.x >> 6);
  const int l = threadIdx.x & 63;
  const u16* base = qkv + (size_t)row * (3 * D_);
  float q[12], k[12], v[12];
  #pragma unroll
  for (int h = 0; h < 12; h++) {
    q[h] = bf2f(base[h*64 + l]);
    k[h] = bf2f(base[D_ + h*64 + l]);
    v[h] = bf2f(base[2*D_ + h*64 + l]);
  }
  const size_t ob = (size_t)row * D_;
  #pragma unroll
  for (int i = 0; i < 12; i++) {
    float s[12];
    #pragma unroll
    for (int j = 0; j < 12; j++) s[j] = q[i] * k[j];
    #pragma unroll
    for (int m = 1; m < 64; m <<= 1) {
      #pragma unroll
      for (int j = 0; j < 12; j++) s[j] += __shfl_xor(s[j], m, 64);
    }
    float mx = s[0];
    #pragma unroll
    for (int j = 1; j < 12; j++) mx = fmaxf(mx, s[j]);
    float den = 0.f, acc = 0.f;
    #pragma unroll
    for (int j = 0; j < 12; j++) {
      const float p = __expf((s[j] - mx) * 0.125f);
      den += p; acc += p * v[j];
    }
    o[ob + i*64 + l] = f2bf(acc / den);
  }
}

// ---------------------------------------------------------------------------
extern "C" void kernel_launch(void* const* d_in, const int* in_sizes, int n_in,
                              void* d_out, int out_size, void* d_ws, size_t ws_size,
                              hipStream_t stream)
{
  const float* x    = (const float*)d_in[0];
  const float* ce   = (const float*)d_in[1];
  const float* pe   = (const float*)d_in[2];
  const float* pw   = (const float*)d_in[3];
  const float* pb   = (const float*)d_in[4];
  const float* qkvw = (const float*)d_in[5];
  const float* qkvb = (const float*)d_in[6];
  const float* topw = (const float*)d_in[7];
  const float* topb = (const float*)d_in[8];
  const float* l1w  = (const float*)d_in[9];
  const float* l1b  = (const float*)d_in[10];
  const float* l2w  = (const float*)d_in[11];
  const float* l2b  = (const float*)d_in[12];
  const float* w1   = (const float*)d_in[13];
  const float* b1   = (const float*)d_in[14];
  const float* w2   = (const float*)d_in[15];
  const float* b2   = (const float*)d_in[16];
  const float* l3w  = (const float*)d_in[17];
  const float* l3b  = (const float*)d_in[18];
  const float* hw1  = (const float*)d_in[19];
  const float* hb1  = (const float*)d_in[20];
  const float* hw2  = (const float*)d_in[21];
  const float* hb2  = (const float*)d_in[22];

  char* ws = (char*)d_ws;
  constexpr size_t SZ_Z  = (size_t)MPAD * D_ * 4;
  constexpr size_t SZ_HB = (size_t)MPAD * D_ * 2;
  constexpr size_t SZ_QM = (size_t)MPAD * DM_ * 2;
  constexpr size_t SZ_WB = (size_t)DM_ * 1024 * 2;
  constexpr size_t SZ_YB = (size_t)128 * D_ * 2;
  float* z  = (float*)ws;
  u16*   hb = (u16*)(ws + SZ_Z);
  u16*   qm = (u16*)(ws + SZ_Z + SZ_HB);
  u16*   wb = (u16*)(ws + SZ_Z + SZ_HB + SZ_QM);
  u16*   yb = (u16*)(ws + SZ_Z + SZ_HB + SZ_QM + SZ_WB);
  u16*   t1 = (u16*)(ws + SZ_Z + SZ_HB + SZ_QM + SZ_WB + SZ_YB);

  const dim3 blk(256);
  const dim3 wblk(32, 8);
  const int MT = MPAD / 128;   // 289

  // Patch embedding
  patchify_k<<<B_ * NP_, blk, 0, stream>>>(x, hb);
  wconv_k<<<dim3(D_/32, D_/32), wblk, 0, stream>>>(pw, wb, D_, D_);
  gemm_k<4><<<6*MT, blk, 0, stream>>>(hb, wb, pb, nullptr, z, D_, D_, 6, 0, 0);
  posecls_k<<<MREAL, blk, 0, stream>>>(z, ce, pe);

  for (int i = 0; i < NL_; i++) {
    ln_k<<<MPAD/4, blk, 0, stream>>>(z, l1w + i*D_, l1b + i*D_, hb);
    wconv_k<<<dim3(3*D_/32, D_/32), wblk, 0, stream>>>(qkvw + (size_t)i*D_*3*D_, wb, D_, 3*D_);
    gemm_k<0><<<18*MT, blk, 0, stream>>>(hb, wb, qkvb + i*3*D_, nullptr, qm, D_, 3*D_, 18, 0, 0);
    attn_k<<<MREAL/4, blk, 0, stream>>>(qm, hb);
    wconv_k<<<dim3(D_/32, D_/32), wblk, 0, stream>>>(topw + (size_t)i*D_*D_, wb, D_, D_);
    gemm_k<1><<<6*MT, blk, 0, stream>>>(hb, wb, topb + i*D_, z, z, D_, D_, 6, 0, 0);
    ln_k<<<MPAD/4, blk, 0, stream>>>(z, l2w + i*D_, l2b + i*D_, hb);
    wconv_k<<<dim3(DM_/32, D_/32), wblk, 0, stream>>>(w1 + (size_t)i*D_*DM_, wb, D_, DM_);
    gemm_k<2><<<24*MT, blk, 0, stream>>>(hb, wb, b1 + i*DM_, nullptr, qm, D_, DM_, 24, 0, 0);
    wconv_k<<<dim3(D_/32, DM_/32), wblk, 0, stream>>>(w2 + (size_t)i*DM_*D_, wb, DM_, D_);
    gemm_k<3><<<6*MT, blk, 0, stream>>>(qm, wb, b2 + i*D_, z, z, DM_, D_, 6, 0, 0);
  }

  // Head: LN(cls) -> MLP with gelu after both linears
  lncls_k<<<32, blk, 0, stream>>>(z, l3w, l3b, yb);
  wconv_k<<<dim3(DM_/32, D_/32), wblk, 0, stream>>>(hw1, wb, D_, DM_);
  gemm_k<2><<<24, blk, 0, stream>>>(yb, wb, hb1, nullptr, t1, D_, DM_, 24, 0, 0);
  wconv_k<<<dim3(1024/32, DM_/32), wblk, 0, stream>>>(hw2, wb, DM_, NC_);
  gemm_k<5><<<8, blk, 0, stream>>>(t1, wb, hb2, nullptr, (float*)d_out, DM_, 1024, 8, B_, NC_);
}

// Round 3
// 12501.276 us; speedup vs baseline: 1.3317x; 1.2645x over previous
//
#include <hip/hip_runtime.h>

typedef unsigned short u16;
typedef unsigned int u32;
typedef __bf16 bf16x8 __attribute__((ext_vector_type(8)));
typedef float f32x4 __attribute__((ext_vector_type(4)));

#define D_    768
#define DM_   3072
#define NL_   12
#define NT_   577
#define NP_   576
#define B_    64
#define MREAL (B_*NT_)      /* 36928 */
#define MPAD  36992         /* 289*128 */
#define NC_   1000
#define IMG_  384

__device__ __forceinline__ float bf2f(u16 v){
  union { unsigned u; float f; } c; c.u = ((unsigned)v) << 16; return c.f;
}
__device__ __forceinline__ u16 f2bf(float f){
  union { float f; unsigned u; } c; c.f = f;
  unsigned r = c.u + 0x7FFFu + ((c.u >> 16) & 1u);
  return (u16)(r >> 16);
}
__device__ __forceinline__ float gelu_f(float x){
  return 0.5f * x * (1.0f + erff(x * 0.70710678118654752f));
}
__device__ __forceinline__ void gload16(const void* g, void* l){
  __builtin_amdgcn_global_load_lds((const __attribute__((address_space(1))) void*)g,
                                   (__attribute__((address_space(3))) void*)l, 16, 0, 0);
}

// ---------------------------------------------------------------------------
// GEMM: C[M,N] = A[M,K] (bf16, row-major) x Bt[N,K] (bf16, N-major = B^T)
// 128x128 tile, BK=64, 4 waves 2x2, 16x16x32 MFMA, 4x4 acc per wave.
// LDS XOR swizzle on source + ds_read; bijective XCD swizzle, bn-fastest.
// EPI: 0=bf16 bias, 1=f32 bias+res, 2=bf16 gelu(bias), 3=f32 gelu(bias)+res,
//      4=f32 bias, 5=f32 gelu(bias) bounded store [Ms,Ns]
// ---------------------------------------------------------------------------
template<int EPI>
__global__ __launch_bounds__(256) void gemm_k(
    const u16* __restrict__ A, const u16* __restrict__ Bt,
    const float* __restrict__ bias, const float* __restrict__ res,
    void* __restrict__ outv, int K, int ldo, int nbn, int Ms, int Ns)
{
  __shared__ u16 As[128*64];
  __shared__ u16 Bs[128*64];
  const int tid = threadIdx.x;
  const int l   = tid & 63;
  const int w   = tid >> 6;
  const int wm  = w >> 1, wn = w & 1;
  const int lrow = l & 15;

  const int nwg = gridDim.x;
  const int q = nwg >> 3, r = nwg & 7;
  const int xcd = blockIdx.x & 7, o = blockIdx.x >> 3;
  const int wg = (xcd < r ? xcd * (q + 1) : r * (q + 1) + (xcd - r) * q) + o;
  const int bm = wg / nbn, bn = wg % nbn;

  const int cs8 = ((tid & 7) ^ ((tid >> 3) & 7)) * 8;
  const int rb  = tid >> 3;                       // 0..31
  const size_t abase = (size_t)bm * 128 * K;
  const size_t bbase = (size_t)bn * 128 * K;
  size_t aoff[4], boff[4];
  #pragma unroll
  for (int i = 0; i < 4; i++) {
    aoff[i] = abase + (size_t)(rb + 32 * i) * K + cs8;
    boff[i] = bbase + (size_t)(rb + 32 * i) * K + cs8;
  }

  const int colA = (l >> 4) << 4;
  const int sw   = (lrow & 7) << 4;

  f32x4 acc[4][4];
  #pragma unroll
  for (int i = 0; i < 4; i++)
    #pragma unroll
    for (int j = 0; j < 4; j++) acc[i][j] = {0.f, 0.f, 0.f, 0.f};

  const int nk = K >> 6;
  for (int kt = 0; kt < nk; ++kt) {
    const int koff = kt * 64;
    #pragma unroll
    for (int i = 0; i < 4; i++) {
      gload16(A  + aoff[i] + koff, As + tid * 8 + i * 2048);
      gload16(Bt + boff[i] + koff, Bs + tid * 8 + i * 2048);
    }
    __syncthreads();
    #pragma unroll
    for (int kk = 0; kk < 2; kk++) {
      bf16x8 af[4], bfr[4];
      #pragma unroll
      for (int mi = 0; mi < 4; mi++)
        af[mi] = *(const bf16x8*)((const char*)As +
                  ((wm*64 + mi*16 + lrow) << 7) + (((kk << 6) | colA) ^ sw));
      #pragma unroll
      for (int ni = 0; ni < 4; ni++)
        bfr[ni] = *(const bf16x8*)((const char*)Bs +
                  ((wn*64 + ni*16 + lrow) << 7) + (((kk << 6) | colA) ^ sw));
      #pragma unroll
      for (int mi = 0; mi < 4; mi++)
        #pragma unroll
        for (int ni = 0; ni < 4; ni++)
          acc[mi][ni] = __builtin_amdgcn_mfma_f32_16x16x32_bf16(af[mi], bfr[ni], acc[mi][ni], 0, 0, 0);
    }
    __syncthreads();
  }

  const int orow0 = bm*128 + wm*64;
  const int ocol0 = bn*128 + wn*64;
  #pragma unroll
  for (int mi = 0; mi < 4; mi++) {
    #pragma unroll
    for (int ni = 0; ni < 4; ni++) {
      #pragma unroll
      for (int r2 = 0; r2 < 4; r2++) {
        const int row = orow0 + mi*16 + (l >> 4)*4 + r2;
        const int col = ocol0 + ni*16 + (l & 15);
        float bv;
        if constexpr (EPI == 5) bv = (col < Ns) ? bias[col] : 0.f;
        else bv = bias[col];
        const float v = acc[mi][ni][r2] + bv;
        const size_t idx = (size_t)row * ldo + col;
        if constexpr (EPI == 0) ((u16*)outv)[idx] = f2bf(v);
        else if constexpr (EPI == 1) ((float*)outv)[idx] = v + res[idx];
        else if constexpr (EPI == 2) ((u16*)outv)[idx] = f2bf(gelu_f(v));
        else if constexpr (EPI == 3) ((float*)outv)[idx] = gelu_f(v) + res[idx];
        else if constexpr (EPI == 4) ((float*)outv)[idx] = v;
        else if constexpr (EPI == 5) {
          if (row < Ms && col < Ns) ((float*)outv)[(size_t)row * Ns + col] = gelu_f(v);
        }
      }
    }
  }
}

// ---------------------------------------------------------------------------
__global__ void wconv_k(const float* __restrict__ W, u16* __restrict__ Wt,
                        int K, int N)
{
  __shared__ float tile[32][33];
  const int n0 = blockIdx.x * 32, k0 = blockIdx.y * 32;
  const int tx = threadIdx.x, ty = threadIdx.y;
  #pragma unroll
  for (int r = 0; r < 4; r++) {
    const int kk = k0 + ty + r*8;
    const int nn = n0 + tx;
    tile[ty + r*8][tx] = (nn < N) ? W[(size_t)kk * N + nn] : 0.f;
  }
  __syncthreads();
  #pragma unroll
  for (int r = 0; r < 4; r++) {
    const int nn = n0 + ty + r*8;
    Wt[(size_t)nn * K + k0 + tx] = f2bf(tile[tx][ty + r*8]);
  }
}

// ---------------------------------------------------------------------------
__global__ void patchify_k(const float* __restrict__ x, u16* __restrict__ hb)
{
  const int blk = blockIdx.x;
  const int b = blk / NP_, p = blk % NP_;
  const int pr = p / 24, pc = p % 24;
  const size_t row = (size_t)b * NT_ + 1 + p;
  #pragma unroll
  for (int u = 0; u < 3; u++) {
    const int j  = threadIdx.x + u * 256;
    const int c  = j >> 8, ph = (j >> 4) & 15, pw = j & 15;
    const float v = x[((size_t)(b*3 + c) * IMG_ + pr*16 + ph) * IMG_ + pc*16 + pw];
    hb[row * D_ + j] = f2bf(v);
  }
}

__global__ void posecls_k(float* __restrict__ z, const float* __restrict__ ce,
                          const float* __restrict__ pe)
{
  const int row = blockIdx.x;
  const int t = row % NT_;
  const size_t base = (size_t)row * D_;
  #pragma unroll
  for (int u = 0; u < 3; u++) {
    const int j = threadIdx.x + u * 256;
    if (t == 0) z[base + j] = ce[j] + pe[j];
    else        z[base + j] += pe[(size_t)t * D_ + j];
  }
}

// LayerNorm: one wave per row, float4 loads, f32 in -> bf16 out
__global__ void ln_k(const float* __restrict__ z, const float* __restrict__ w,
                     const float* __restrict__ b, u16* __restrict__ out)
{
  const int row = blockIdx.x * 4 + (threadIdx.x >> 6);
  const int l = threadIdx.x & 63;
  const float4* zr = (const float4*)(z + (size_t)row * D_);
  float4 xq[3];
  float s = 0.f;
  #pragma unroll
  for (int j = 0; j < 3; j++) {
    xq[j] = zr[j*64 + l];
    s += xq[j].x + xq[j].y + xq[j].z + xq[j].w;
  }
  #pragma unroll
  for (int m = 1; m < 64; m <<= 1) s += __shfl_xor(s, m, 64);
  const float mean = s * (1.0f / 768.0f);
  float ss = 0.f;
  #pragma unroll
  for (int j = 0; j < 3; j++) {
    const float dx = xq[j].x-mean, dy = xq[j].y-mean, dz = xq[j].z-mean, dw = xq[j].w-mean;
    ss += dx*dx + dy*dy + dz*dz + dw*dw;
  }
  #pragma unroll
  for (int m = 1; m < 64; m <<= 1) ss += __shfl_xor(ss, m, 64);
  const float rinv = rsqrtf(ss * (1.0f / 768.0f) + 1e-5f);
  const size_t ob = (size_t)row * D_;
  #pragma unroll
  for (int j = 0; j < 3; j++) {
    const int c = (j*64 + l) * 4;
    const float4 wv = *(const float4*)(w + c);
    const float4 bv = *(const float4*)(b + c);
    ushort4 ov;
    ov.x = f2bf((xq[j].x - mean) * rinv * wv.x + bv.x);
    ov.y = f2bf((xq[j].y - mean) * rinv * wv.y + bv.y);
    ov.z = f2bf((xq[j].z - mean) * rinv * wv.z + bv.z);
    ov.w = f2bf((xq[j].w - mean) * rinv * wv.w + bv.w);
    *(ushort4*)(out + ob + c) = ov;
  }
}

// Final LN over cls rows -> yb[128][768] bf16 (rows >= 64 zeroed)
__global__ void lncls_k(const float* __restrict__ z, const float* __restrict__ w,
                        const float* __restrict__ b, u16* __restrict__ out)
{
  const int row = blockIdx.x * 4 + (threadIdx.x >> 6);   // 0..127
  const int l = threadIdx.x & 63;
  const size_t ob = (size_t)row * D_;
  if (row >= B_) {
    #pragma unroll
    for (int j = 0; j < 12; j++) out[ob + j*64 + l] = 0;
    return;
  }
  const float* zr = z + (size_t)row * NT_ * D_;
  float xv[12];
  float s = 0.f;
  #pragma unroll
  for (int j = 0; j < 12; j++) { xv[j] = zr[j*64 + l]; s += xv[j]; }
  #pragma unroll
  for (int m = 1; m < 64; m <<= 1) s += __shfl_xor(s, m, 64);
  const float mean = s * (1.0f / 768.0f);
  float ss = 0.f;
  #pragma unroll
  for (int j = 0; j < 12; j++) { const float d = xv[j] - mean; ss += d * d; }
  #pragma unroll
  for (int m = 1; m < 64; m <<= 1) ss += __shfl_xor(ss, m, 64);
  const float rinv = rsqrtf(ss * (1.0f / 768.0f) + 1e-5f);
  #pragma unroll
  for (int j = 0; j < 12; j++) {
    const int cidx = j*64 + l;
    out[ob + cidx] = f2bf((xv[j] - mean) * rinv * w[cidx] + b[cidx]);
  }
}

// ---------------------------------------------------------------------------
// MFMA per-token head-axis attention. One wave per token, no LDS.
// S^T = K·Q^T via 2x mfma_16x16x32 (heads padded 12->16, garbage masked).
// Softmax over C rows (in-lane 4 + shfl_xor 16/32), 1/den folded into P.
// O^T = V^T·P^T via 4x mfma (d-tiles); P^T B-frag built by 4 __shfl.
// ---------------------------------------------------------------------------
__global__ __launch_bounds__(256) void attn_k(const u16* __restrict__ qkv,
                                              u16* __restrict__ o)
{
  const int tok = (blockIdx.x * 256 + threadIdx.x) >> 6;
  const int l  = threadIdx.x & 63;
  const int g  = l >> 4, li = l & 15;
  const size_t rb = (size_t)tok * (3 * D_);

  // S^T = K Q^T  (rows j = 4g+r, cols i = li)
  f32x4 s = {0.f, 0.f, 0.f, 0.f};
  #pragma unroll
  for (int kt = 0; kt < 2; kt++) {
    const bf16x8 ka = *(const bf16x8*)(qkv + rb + D_ + li*64 + g*8 + kt*32);
    const bf16x8 qb = *(const bf16x8*)(qkv + rb +      li*64 + g*8 + kt*32);
    s = __builtin_amdgcn_mfma_f32_16x16x32_bf16(ka, qb, s, 0, 0, 0);
  }

  // softmax over j (rows), scale 1/8
  float sv[4];
  #pragma unroll
  for (int r2 = 0; r2 < 4; r2++) sv[r2] = s[r2] * 0.125f;
  float mx = (g < 3) ? fmaxf(fmaxf(sv[0], sv[1]), fmaxf(sv[2], sv[3])) : -1e30f;
  mx = fmaxf(mx, __shfl_xor(mx, 16, 64));
  mx = fmaxf(mx, __shfl_xor(mx, 32, 64));
  float p[4], den = 0.f;
  #pragma unroll
  for (int r2 = 0; r2 < 4; r2++) {
    p[r2] = (g < 3) ? __expf(sv[r2] - mx) : 0.f;
    den += p[r2];
  }
  den += __shfl_xor(den, 16, 64);
  den += __shfl_xor(den, 32, 64);
  const float rden = 1.0f / den;
  #pragma unroll
  for (int r2 = 0; r2 < 4; r2++) p[r2] *= rden;

  // pack P rows (j=4g+r) as bf16 pairs
  const u32 pk01 = ((u32)f2bf(p[1]) << 16) | f2bf(p[0]);
  const u32 pk23 = ((u32)f2bf(p[3]) << 16) | f2bf(p[2]);

  // B-frag for PV: elems 0-3 <- group 2g, elems 4-7 <- group 2g+1
  const int srcA = (li + (g << 5)) & 63;
  const int srcB = (srcA + 16) & 63;
  u32 b0 = (u32)__shfl((int)pk01, srcA, 64);
  u32 b1 = (u32)__shfl((int)pk23, srcA, 64);
  u32 b2 = (u32)__shfl((int)pk01, srcB, 64);
  u32 b3 = (u32)__shfl((int)pk23, srcB, 64);
  if (g >= 2) { b0 = 0; b1 = 0; b2 = 0; b3 = 0; }
  union { u32 u[4]; bf16x8 v; } pb;
  pb.u[0] = b0; pb.u[1] = b1; pb.u[2] = b2; pb.u[3] = b3;

  // O^T = V^T P^T per 16-wide d-tile
  const size_t ob = (size_t)tok * D_;
  #pragma unroll
  for (int t = 0; t < 4; t++) {
    union { u16 a[8]; bf16x8 v; } va;
    #pragma unroll
    for (int jp = 0; jp < 8; jp++) {
      const int j = g * 8 + jp;
      va.a[jp] = (j < 12) ? qkv[rb + 2*D_ + j*64 + t*16 + li] : (u16)0;
    }
    f32x4 oac = {0.f, 0.f, 0.f, 0.f};
    oac = __builtin_amdgcn_mfma_f32_16x16x32_bf16(va.v, pb.v, oac, 0, 0, 0);
    if (li < 12) {
      ushort4 ov;
      ov.x = f2bf(oac[0]); ov.y = f2bf(oac[1]);
      ov.z = f2bf(oac[2]); ov.w = f2bf(oac[3]);
      *(ushort4*)(o + ob + li*64 + t*16 + g*4) = ov;
    }
  }
}

// ---------------------------------------------------------------------------
extern "C" void kernel_launch(void* const* d_in, const int* in_sizes, int n_in,
                              void* d_out, int out_size, void* d_ws, size_t ws_size,
                              hipStream_t stream)
{
  const float* x    = (const float*)d_in[0];
  const float* ce   = (const float*)d_in[1];
  const float* pe   = (const float*)d_in[2];
  const float* pw   = (const float*)d_in[3];
  const float* pb   = (const float*)d_in[4];
  const float* qkvw = (const float*)d_in[5];
  const float* qkvb = (const float*)d_in[6];
  const float* topw = (const float*)d_in[7];
  const float* topb = (const float*)d_in[8];
  const float* l1w  = (const float*)d_in[9];
  const float* l1b  = (const float*)d_in[10];
  const float* l2w  = (const float*)d_in[11];
  const float* l2b  = (const float*)d_in[12];
  const float* w1   = (const float*)d_in[13];
  const float* b1   = (const float*)d_in[14];
  const float* w2   = (const float*)d_in[15];
  const float* b2   = (const float*)d_in[16];
  const float* l3w  = (const float*)d_in[17];
  const float* l3b  = (const float*)d_in[18];
  const float* hw1  = (const float*)d_in[19];
  const float* hb1  = (const float*)d_in[20];
  const float* hw2  = (const float*)d_in[21];
  const float* hb2  = (const float*)d_in[22];

  char* ws = (char*)d_ws;
  constexpr size_t SZ_Z  = (size_t)MPAD * D_ * 4;
  constexpr size_t SZ_HB = (size_t)MPAD * D_ * 2;
  constexpr size_t SZ_QM = (size_t)MPAD * DM_ * 2;
  constexpr size_t SZ_WB = (size_t)DM_ * 1024 * 2;
  constexpr size_t SZ_YB = (size_t)128 * D_ * 2;
  float* z  = (float*)ws;
  u16*   hb = (u16*)(ws + SZ_Z);
  u16*   qm = (u16*)(ws + SZ_Z + SZ_HB);
  u16*   wb = (u16*)(ws + SZ_Z + SZ_HB + SZ_QM);
  u16*   yb = (u16*)(ws + SZ_Z + SZ_HB + SZ_QM + SZ_WB);
  u16*   t1 = (u16*)(ws + SZ_Z + SZ_HB + SZ_QM + SZ_WB + SZ_YB);

  const dim3 blk(256);
  const dim3 wblk(32, 8);
  const int MT = MPAD / 128;   // 289

  // Patch embedding
  patchify_k<<<B_ * NP_, blk, 0, stream>>>(x, hb);
  wconv_k<<<dim3(D_/32, D_/32), wblk, 0, stream>>>(pw, wb, D_, D_);
  gemm_k<4><<<6*MT, blk, 0, stream>>>(hb, wb, pb, nullptr, z, D_, D_, 6, 0, 0);
  posecls_k<<<MREAL, blk, 0, stream>>>(z, ce, pe);

  for (int i = 0; i < NL_; i++) {
    ln_k<<<MPAD/4, blk, 0, stream>>>(z, l1w + i*D_, l1b + i*D_, hb);
    wconv_k<<<dim3(3*D_/32, D_/32), wblk, 0, stream>>>(qkvw + (size_t)i*D_*3*D_, wb, D_, 3*D_);
    gemm_k<0><<<18*MT, blk, 0, stream>>>(hb, wb, qkvb + i*3*D_, nullptr, qm, D_, 3*D_, 18, 0, 0);
    attn_k<<<MREAL/4, blk, 0, stream>>>(qm, hb);
    wconv_k<<<dim3(D_/32, D_/32), wblk, 0, stream>>>(topw + (size_t)i*D_*D_, wb, D_, D_);
    gemm_k<1><<<6*MT, blk, 0, stream>>>(hb, wb, topb + i*D_, z, z, D_, D_, 6, 0, 0);
    ln_k<<<MPAD/4, blk, 0, stream>>>(z, l2w + i*D_, l2b + i*D_, hb);
    wconv_k<<<dim3(DM_/32, D_/32), wblk, 0, stream>>>(w1 + (size_t)i*D_*DM_, wb, D_, DM_);
    gemm_k<2><<<24*MT, blk, 0, stream>>>(hb, wb, b1 + i*DM_, nullptr, qm, D_, DM_, 24, 0, 0);
    wconv_k<<<dim3(D_/32, DM_/32), wblk, 0, stream>>>(w2 + (size_t)i*DM_*D_, wb, DM_, D_);
    gemm_k<3><<<6*MT, blk, 0, stream>>>(qm, wb, b2 + i*D_, z, z, DM_, D_, 6, 0, 0);
  }

  // Head: LN(cls) -> MLP with gelu after both linears
  lncls_k<<<32, blk, 0, stream>>>(z, l3w, l3b, yb);
  wconv_k<<<dim3(DM_/32, D_/32), wblk, 0, stream>>>(hw1, wb, D_, DM_);
  gemm_k<2><<<24, blk, 0, stream>>>(yb, wb, hb1, nullptr, t1, D_, DM_, 24, 0, 0);
  wconv_k<<<dim3(1024/32, DM_/32), wblk, 0, stream>>>(hw2, wb, DM_, NC_);
  gemm_k<5><<<8, blk, 0, stream>>>(t1, wb, hb2, nullptr, (float*)d_out, DM_, 1024, 8, B_, NC_);
}

// Round 4
// 11851.740 us; speedup vs baseline: 1.4047x; 1.0548x over previous
//
#include <hip/hip_runtime.h>

typedef unsigned short u16;
typedef unsigned int u32;
typedef __bf16 bf16x8 __attribute__((ext_vector_type(8)));
typedef float f32x4 __attribute__((ext_vector_type(4)));

#define D_    768
#define DM_   3072
#define NL_   12
#define NT_   577
#define NP_   576
#define B_    64
#define MREAL (B_*NT_)      /* 36928 */
#define MPAD2 37120         /* 145*256 */
#define NC_   1000
#define IMG_  384

__device__ __forceinline__ float bf2f(u16 v){
  union { unsigned u; float f; } c; c.u = ((unsigned)v) << 16; return c.f;
}
__device__ __forceinline__ u16 f2bf(float f){
  union { float f; unsigned u; } c; c.f = f;
  unsigned r = c.u + 0x7FFFu + ((c.u >> 16) & 1u);
  return (u16)(r >> 16);
}
__device__ __forceinline__ float gelu_f(float x){
  return 0.5f * x * (1.0f + erff(x * 0.70710678118654752f));
}
__device__ __forceinline__ void gload16(const void* g, void* l){
  __builtin_amdgcn_global_load_lds((const __attribute__((address_space(1))) void*)g,
                                   (__attribute__((address_space(3))) void*)l, 16, 0, 0);
}

// ---------------------------------------------------------------------------
// 256x256 double-buffered GEMM, BK=64, 8 waves (2Mx4N), counted vmcnt(8).
// C[M,N] = A[M,K] bf16 row-major x Bt[N,K] bf16. LDS 128 KiB (2 dbuf x A,B).
// Proven XOR swizzle: source col8 ^= row&7, ds_read byte ^= (lrow&7)<<4.
// Body t: stage(t+1 -> dbuf^1); vmcnt(8); barrier; compute(dbuf); barrier.
// EPI: 0=bf16 bias, 1=f32 bias+res, 2=bf16 gelu(bias), 3=f32 gelu(bias)+res,
//      4=f32 bias
// ---------------------------------------------------------------------------
template<int EPI>
__global__ __launch_bounds__(512, 1) void gemm256_k(
    const u16* __restrict__ A, const u16* __restrict__ Bt,
    const float* __restrict__ bias, const float* __restrict__ res,
    void* __restrict__ outv, int K, int ldo, int nbn)
{
  __shared__ u16 lds[2][2][256*64];
  const int tid = threadIdx.x;
  const int l   = tid & 63;
  const int wid = tid >> 6;
  const int wm  = wid >> 2, wn = wid & 3;
  const int lrow = l & 15;

  // bijective XCD swizzle (m204), bn-fastest
  const int nwg = gridDim.x;
  const int q = nwg >> 3, r = nwg & 7;
  const int xcd = blockIdx.x & 7, o = blockIdx.x >> 3;
  const int wg = (xcd < r ? xcd * (q + 1) : r * (q + 1) + (xcd - r) * q) + o;
  const int bm = wg / nbn, bn = wg % nbn;

  // staging: c = tid + 512*i -> row = c>>3 (0..255), col8 = c&7; src pre-swizzle
  const int cs8 = ((tid & 7) ^ ((tid >> 3) & 7)) * 8;
  const int rb  = tid >> 3;                       // 0..63
  const u16* aP[4]; const u16* bP[4];
  #pragma unroll
  for (int i = 0; i < 4; i++) {
    aP[i] = A  + (size_t)(bm*256 + rb + 64*i) * K + cs8;
    bP[i] = Bt + (size_t)(bn*256 + rb + 64*i) * K + cs8;
  }
  const int ldst = tid * 8;

  f32x4 acc[8][4];
  #pragma unroll
  for (int i = 0; i < 8; i++)
    #pragma unroll
    for (int j = 0; j < 4; j++) acc[i][j] = {0.f, 0.f, 0.f, 0.f};

  const int nk = K >> 6;
  // prologue: stage tile 0 -> dbuf 0
  #pragma unroll
  for (int i = 0; i < 4; i++) {
    gload16(aP[i], &lds[0][0][ldst + i*4096]);
    gload16(bP[i], &lds[0][1][ldst + i*4096]);
    aP[i] += 64; bP[i] += 64;
  }

  const int sw  = (lrow & 7) << 4;
  const int g16 = (l >> 4) << 4;

  for (int t = 0; t < nk; ++t) {
    const int cur = t & 1;
    if (t + 1 < nk) {
      #pragma unroll
      for (int i = 0; i < 4; i++) {
        gload16(aP[i], &lds[cur^1][0][ldst + i*4096]);
        gload16(bP[i], &lds[cur^1][1][ldst + i*4096]);
        aP[i] += 64; bP[i] += 64;
      }
      __builtin_amdgcn_sched_barrier(0);
      asm volatile("s_waitcnt vmcnt(8)" ::: "memory");
    } else {
      __builtin_amdgcn_sched_barrier(0);
      asm volatile("s_waitcnt vmcnt(0)" ::: "memory");
    }
    __builtin_amdgcn_sched_barrier(0);
    __builtin_amdgcn_s_barrier();
    __builtin_amdgcn_sched_barrier(0);
    const char* As_ = (const char*)&lds[cur][0][0];
    const char* Bs_ = (const char*)&lds[cur][1][0];
    #pragma unroll
    for (int kk = 0; kk < 2; kk++) {
      bf16x8 af[8], bfr[4];
      const int kb = (kk << 6) | g16;
      #pragma unroll
      for (int mi = 0; mi < 8; mi++)
        af[mi] = *(const bf16x8*)(As_ + ((wm*128 + mi*16 + lrow) << 7) + (kb ^ sw));
      #pragma unroll
      for (int ni = 0; ni < 4; ni++)
        bfr[ni] = *(const bf16x8*)(Bs_ + ((wn*64 + ni*16 + lrow) << 7) + (kb ^ sw));
      #pragma unroll
      for (int mi = 0; mi < 8; mi++)
        #pragma unroll
        for (int ni = 0; ni < 4; ni++)
          acc[mi][ni] = __builtin_amdgcn_mfma_f32_16x16x32_bf16(af[mi], bfr[ni], acc[mi][ni], 0, 0, 0);
    }
    __builtin_amdgcn_sched_barrier(0);
    __builtin_amdgcn_s_barrier();
    __builtin_amdgcn_sched_barrier(0);
  }

  const int orow0 = bm*256 + wm*128;
  const int ocol0 = bn*256 + wn*64;
  #pragma unroll
  for (int mi = 0; mi < 8; mi++) {
    #pragma unroll
    for (int ni = 0; ni < 4; ni++) {
      const int col = ocol0 + ni*16 + (l & 15);
      const float bv = bias[col];
      #pragma unroll
      for (int r2 = 0; r2 < 4; r2++) {
        const int row = orow0 + mi*16 + (l >> 4)*4 + r2;
        const float v = acc[mi][ni][r2] + bv;
        const size_t idx = (size_t)row * ldo + col;
        if constexpr (EPI == 0) ((u16*)outv)[idx] = f2bf(v);
        else if constexpr (EPI == 1) ((float*)outv)[idx] = v + res[idx];
        else if constexpr (EPI == 2) ((u16*)outv)[idx] = f2bf(gelu_f(v));
        else if constexpr (EPI == 3) ((float*)outv)[idx] = gelu_f(v) + res[idx];
        else if constexpr (EPI == 4) ((float*)outv)[idx] = v;
      }
    }
  }
}

// ---------------------------------------------------------------------------
// 128x128 single-buffered GEMM (round-3 proven) — kept for small head GEMMs.
// EPI: 2=bf16 gelu(bias), 5=f32 gelu(bias) bounded store [Ms,Ns]
// ---------------------------------------------------------------------------
template<int EPI>
__global__ __launch_bounds__(256) void gemm_k(
    const u16* __restrict__ A, const u16* __restrict__ Bt,
    const float* __restrict__ bias, const float* __restrict__ res,
    void* __restrict__ outv, int K, int ldo, int nbn, int Ms, int Ns)
{
  __shared__ u16 As[128*64];
  __shared__ u16 Bs[128*64];
  const int tid = threadIdx.x;
  const int l   = tid & 63;
  const int w   = tid >> 6;
  const int wm  = w >> 1, wn = w & 1;
  const int lrow = l & 15;

  const int nwg = gridDim.x;
  const int q = nwg >> 3, r = nwg & 7;
  const int xcd = blockIdx.x & 7, o = blockIdx.x >> 3;
  const int wg = (xcd < r ? xcd * (q + 1) : r * (q + 1) + (xcd - r) * q) + o;
  const int bm = wg / nbn, bn = wg % nbn;

  const int cs8 = ((tid & 7) ^ ((tid >> 3) & 7)) * 8;
  const int rb  = tid >> 3;
  const size_t abase = (size_t)bm * 128 * K;
  const size_t bbase = (size_t)bn * 128 * K;
  size_t aoff[4], boff[4];
  #pragma unroll
  for (int i = 0; i < 4; i++) {
    aoff[i] = abase + (size_t)(rb + 32 * i) * K + cs8;
    boff[i] = bbase + (size_t)(rb + 32 * i) * K + cs8;
  }

  const int colA = (l >> 4) << 4;
  const int sw   = (lrow & 7) << 4;

  f32x4 acc[4][4];
  #pragma unroll
  for (int i = 0; i < 4; i++)
    #pragma unroll
    for (int j = 0; j < 4; j++) acc[i][j] = {0.f, 0.f, 0.f, 0.f};

  const int nk = K >> 6;
  for (int kt = 0; kt < nk; ++kt) {
    const int koff = kt * 64;
    #pragma unroll
    for (int i = 0; i < 4; i++) {
      gload16(A  + aoff[i] + koff, As + tid * 8 + i * 2048);
      gload16(Bt + boff[i] + koff, Bs + tid * 8 + i * 2048);
    }
    __syncthreads();
    #pragma unroll
    for (int kk = 0; kk < 2; kk++) {
      bf16x8 af[4], bfr[4];
      #pragma unroll
      for (int mi = 0; mi < 4; mi++)
        af[mi] = *(const bf16x8*)((const char*)As +
                  ((wm*64 + mi*16 + lrow) << 7) + (((kk << 6) | colA) ^ sw));
      #pragma unroll
      for (int ni = 0; ni < 4; ni++)
        bfr[ni] = *(const bf16x8*)((const char*)Bs +
                  ((wn*64 + ni*16 + lrow) << 7) + (((kk << 6) | colA) ^ sw));
      #pragma unroll
      for (int mi = 0; mi < 4; mi++)
        #pragma unroll
        for (int ni = 0; ni < 4; ni++)
          acc[mi][ni] = __builtin_amdgcn_mfma_f32_16x16x32_bf16(af[mi], bfr[ni], acc[mi][ni], 0, 0, 0);
    }
    __syncthreads();
  }

  const int orow0 = bm*128 + wm*64;
  const int ocol0 = bn*128 + wn*64;
  #pragma unroll
  for (int mi = 0; mi < 4; mi++) {
    #pragma unroll
    for (int ni = 0; ni < 4; ni++) {
      #pragma unroll
      for (int r2 = 0; r2 < 4; r2++) {
        const int row = orow0 + mi*16 + (l >> 4)*4 + r2;
        const int col = ocol0 + ni*16 + (l & 15);
        float bv;
        if constexpr (EPI == 5) bv = (col < Ns) ? bias[col] : 0.f;
        else bv = bias[col];
        const float v = acc[mi][ni][r2] + bv;
        const size_t idx = (size_t)row * ldo + col;
        if constexpr (EPI == 2) ((u16*)outv)[idx] = f2bf(gelu_f(v));
        else if constexpr (EPI == 5) {
          if (row < Ms && col < Ns) ((float*)outv)[(size_t)row * Ns + col] = gelu_f(v);
        }
      }
    }
  }
}

// ---------------------------------------------------------------------------
__global__ void wconv_k(const float* __restrict__ W, u16* __restrict__ Wt,
                        int K, int N)
{
  __shared__ float tile[32][33];
  const int n0 = blockIdx.x * 32, k0 = blockIdx.y * 32;
  const int tx = threadIdx.x, ty = threadIdx.y;
  #pragma unroll
  for (int r = 0; r < 4; r++) {
    const int kk = k0 + ty + r*8;
    const int nn = n0 + tx;
    tile[ty + r*8][tx] = (nn < N) ? W[(size_t)kk * N + nn] : 0.f;
  }
  __syncthreads();
  #pragma unroll
  for (int r = 0; r < 4; r++) {
    const int nn = n0 + ty + r*8;
    Wt[(size_t)nn * K + k0 + tx] = f2bf(tile[tx][ty + r*8]);
  }
}

// ---------------------------------------------------------------------------
__global__ void patchify_k(const float* __restrict__ x, u16* __restrict__ hb)
{
  const int blk = blockIdx.x;
  const int b = blk / NP_, p = blk % NP_;
  const int pr = p / 24, pc = p % 24;
  const size_t row = (size_t)b * NT_ + 1 + p;
  #pragma unroll
  for (int u = 0; u < 3; u++) {
    const int j  = threadIdx.x + u * 256;
    const int c  = j >> 8, ph = (j >> 4) & 15, pw = j & 15;
    const float v = x[((size_t)(b*3 + c) * IMG_ + pr*16 + ph) * IMG_ + pc*16 + pw];
    hb[row * D_ + j] = f2bf(v);
  }
}

__global__ void posecls_k(float* __restrict__ z, const float* __restrict__ ce,
                          const float* __restrict__ pe)
{
  const int row = blockIdx.x;
  const int t = row % NT_;
  const size_t base = (size_t)row * D_;
  #pragma unroll
  for (int u = 0; u < 3; u++) {
    const int j = threadIdx.x + u * 256;
    if (t == 0) z[base + j] = ce[j] + pe[j];
    else        z[base + j] += pe[(size_t)t * D_ + j];
  }
}

// LayerNorm: one wave per row, float4 loads, f32 in -> bf16 out
__global__ void ln_k(const float* __restrict__ z, const float* __restrict__ w,
                     const float* __restrict__ b, u16* __restrict__ out)
{
  const int row = blockIdx.x * 4 + (threadIdx.x >> 6);
  const int l = threadIdx.x & 63;
  const float4* zr = (const float4*)(z + (size_t)row * D_);
  float4 xq[3];
  float s = 0.f;
  #pragma unroll
  for (int j = 0; j < 3; j++) {
    xq[j] = zr[j*64 + l];
    s += xq[j].x + xq[j].y + xq[j].z + xq[j].w;
  }
  #pragma unroll
  for (int m = 1; m < 64; m <<= 1) s += __shfl_xor(s, m, 64);
  const float mean = s * (1.0f / 768.0f);
  float ss = 0.f;
  #pragma unroll
  for (int j = 0; j < 3; j++) {
    const float dx = xq[j].x-mean, dy = xq[j].y-mean, dz = xq[j].z-mean, dw = xq[j].w-mean;
    ss += dx*dx + dy*dy + dz*dz + dw*dw;
  }
  #pragma unroll
  for (int m = 1; m < 64; m <<= 1) ss += __shfl_xor(ss, m, 64);
  const float rinv = rsqrtf(ss * (1.0f / 768.0f) + 1e-5f);
  const size_t ob = (size_t)row * D_;
  #pragma unroll
  for (int j = 0; j < 3; j++) {
    const int c = (j*64 + l) * 4;
    const float4 wv = *(const float4*)(w + c);
    const float4 bv = *(const float4*)(b + c);
    ushort4 ov;
    ov.x = f2bf((xq[j].x - mean) * rinv * wv.x + bv.x);
    ov.y = f2bf((xq[j].y - mean) * rinv * wv.y + bv.y);
    ov.z = f2bf((xq[j].z - mean) * rinv * wv.z + bv.z);
    ov.w = f2bf((xq[j].w - mean) * rinv * wv.w + bv.w);
    *(ushort4*)(out + ob + c) = ov;
  }
}

// Final LN over cls rows -> yb[128][768] bf16 (rows >= 64 zeroed)
__global__ void lncls_k(const float* __restrict__ z, const float* __restrict__ w,
                        const float* __restrict__ b, u16* __restrict__ out)
{
  const int row = blockIdx.x * 4 + (threadIdx.x >> 6);   // 0..127
  const int l = threadIdx.x & 63;
  const size_t ob = (size_t)row * D_;
  if (row >= B_) {
    #pragma unroll
    for (int j = 0; j < 12; j++) out[ob + j*64 + l] = 0;
    return;
  }
  const float* zr = z + (size_t)row * NT_ * D_;
  float xv[12];
  float s = 0.f;
  #pragma unroll
  for (int j = 0; j < 12; j++) { xv[j] = zr[j*64 + l]; s += xv[j]; }
  #pragma unroll
  for (int m = 1; m < 64; m <<= 1) s += __shfl_xor(s, m, 64);
  const float mean = s * (1.0f / 768.0f);
  float ss = 0.f;
  #pragma unroll
  for (int j = 0; j < 12; j++) { const float d = xv[j] - mean; ss += d * d; }
  #pragma unroll
  for (int m = 1; m < 64; m <<= 1) ss += __shfl_xor(ss, m, 64);
  const float rinv = rsqrtf(ss * (1.0f / 768.0f) + 1e-5f);
  #pragma unroll
  for (int j = 0; j < 12; j++) {
    const int cidx = j*64 + l;
    out[ob + cidx] = f2bf((xv[j] - mean) * rinv * w[cidx] + b[cidx]);
  }
}

// ---------------------------------------------------------------------------
// MFMA per-token head-axis attention (round-3 proven).
// ---------------------------------------------------------------------------
__global__ __launch_bounds__(256) void attn_k(const u16* __restrict__ qkv,
                                              u16* __restrict__ o)
{
  const int tok = (blockIdx.x * 256 + threadIdx.x) >> 6;
  const int l  = threadIdx.x & 63;
  const int g  = l >> 4, li = l & 15;
  const size_t rb = (size_t)tok * (3 * D_);

  f32x4 s = {0.f, 0.f, 0.f, 0.f};
  #pragma unroll
  for (int kt = 0; kt < 2; kt++) {
    const bf16x8 ka = *(const bf16x8*)(qkv + rb + D_ + li*64 + g*8 + kt*32);
    const bf16x8 qb = *(const bf16x8*)(qkv + rb +      li*64 + g*8 + kt*32);
    s = __builtin_amdgcn_mfma_f32_16x16x32_bf16(ka, qb, s, 0, 0, 0);
  }

  float sv[4];
  #pragma unroll
  for (int r2 = 0; r2 < 4; r2++) sv[r2] = s[r2] * 0.125f;
  float mx = (g < 3) ? fmaxf(fmaxf(sv[0], sv[1]), fmaxf(sv[2], sv[3])) : -1e30f;
  mx = fmaxf(mx, __shfl_xor(mx, 16, 64));
  mx = fmaxf(mx, __shfl_xor(mx, 32, 64));
  float p[4], den = 0.f;
  #pragma unroll
  for (int r2 = 0; r2 < 4; r2++) {
    p[r2] = (g < 3) ? __expf(sv[r2] - mx) : 0.f;
    den += p[r2];
  }
  den += __shfl_xor(den, 16, 64);
  den += __shfl_xor(den, 32, 64);
  const float rden = 1.0f / den;
  #pragma unroll
  for (int r2 = 0; r2 < 4; r2++) p[r2] *= rden;

  const u32 pk01 = ((u32)f2bf(p[1]) << 16) | f2bf(p[0]);
  const u32 pk23 = ((u32)f2bf(p[3]) << 16) | f2bf(p[2]);

  const int srcA = (li + (g << 5)) & 63;
  const int srcB = (srcA + 16) & 63;
  u32 b0 = (u32)__shfl((int)pk01, srcA, 64);
  u32 b1 = (u32)__shfl((int)pk23, srcA, 64);
  u32 b2 = (u32)__shfl((int)pk01, srcB, 64);
  u32 b3 = (u32)__shfl((int)pk23, srcB, 64);
  if (g >= 2) { b0 = 0; b1 = 0; b2 = 0; b3 = 0; }
  union { u32 u[4]; bf16x8 v; } pb;
  pb.u[0] = b0; pb.u[1] = b1; pb.u[2] = b2; pb.u[3] = b3;

  const size_t ob = (size_t)tok * D_;
  #pragma unroll
  for (int t = 0; t < 4; t++) {
    union { u16 a[8]; bf16x8 v; } va;
    #pragma unroll
    for (int jp = 0; jp < 8; jp++) {
      const int j = g * 8 + jp;
      va.a[jp] = (j < 12) ? qkv[rb + 2*D_ + j*64 + t*16 + li] : (u16)0;
    }
    f32x4 oac = {0.f, 0.f, 0.f, 0.f};
    oac = __builtin_amdgcn_mfma_f32_16x16x32_bf16(va.v, pb.v, oac, 0, 0, 0);
    if (li < 12) {
      ushort4 ov;
      ov.x = f2bf(oac[0]); ov.y = f2bf(oac[1]);
      ov.z = f2bf(oac[2]); ov.w = f2bf(oac[3]);
      *(ushort4*)(o + ob + li*64 + t*16 + g*4) = ov;
    }
  }
}

// ---------------------------------------------------------------------------
extern "C" void kernel_launch(void* const* d_in, const int* in_sizes, int n_in,
                              void* d_out, int out_size, void* d_ws, size_t ws_size,
                              hipStream_t stream)
{
  const float* x    = (const float*)d_in[0];
  const float* ce   = (const float*)d_in[1];
  const float* pe   = (const float*)d_in[2];
  const float* pw   = (const float*)d_in[3];
  const float* pb   = (const float*)d_in[4];
  const float* qkvw = (const float*)d_in[5];
  const float* qkvb = (const float*)d_in[6];
  const float* topw = (const float*)d_in[7];
  const float* topb = (const float*)d_in[8];
  const float* l1w  = (const float*)d_in[9];
  const float* l1b  = (const float*)d_in[10];
  const float* l2w  = (const float*)d_in[11];
  const float* l2b  = (const float*)d_in[12];
  const float* w1   = (const float*)d_in[13];
  const float* b1   = (const float*)d_in[14];
  const float* w2   = (const float*)d_in[15];
  const float* b2   = (const float*)d_in[16];
  const float* l3w  = (const float*)d_in[17];
  const float* l3b  = (const float*)d_in[18];
  const float* hw1  = (const float*)d_in[19];
  const float* hb1  = (const float*)d_in[20];
  const float* hw2  = (const float*)d_in[21];
  const float* hb2  = (const float*)d_in[22];

  char* ws = (char*)d_ws;
  constexpr size_t SZ_Z  = (size_t)MPAD2 * D_ * 4;
  constexpr size_t SZ_HB = (size_t)MPAD2 * D_ * 2;
  constexpr size_t SZ_QM = (size_t)MPAD2 * DM_ * 2;
  constexpr size_t SZ_WB = (size_t)DM_ * 1024 * 2;
  constexpr size_t SZ_YB = (size_t)128 * D_ * 2;
  float* z  = (float*)ws;
  u16*   hb = (u16*)(ws + SZ_Z);
  u16*   qm = (u16*)(ws + SZ_Z + SZ_HB);
  u16*   wb = (u16*)(ws + SZ_Z + SZ_HB + SZ_QM);
  u16*   yb = (u16*)(ws + SZ_Z + SZ_HB + SZ_QM + SZ_WB);
  u16*   t1 = (u16*)(ws + SZ_Z + SZ_HB + SZ_QM + SZ_WB + SZ_YB);

  const dim3 blk(256);
  const dim3 blk5(512);
  const dim3 wblk(32, 8);
  const int MT2 = MPAD2 / 256;  // 145

  // Patch embedding
  patchify_k<<<B_ * NP_, blk, 0, stream>>>(x, hb);
  wconv_k<<<dim3(D_/32, D_/32), wblk, 0, stream>>>(pw, wb, D_, D_);
  gemm256_k<4><<<3*MT2, blk5, 0, stream>>>(hb, wb, pb, nullptr, z, D_, D_, 3);
  posecls_k<<<MREAL, blk, 0, stream>>>(z, ce, pe);

  for (int i = 0; i < NL_; i++) {
    ln_k<<<MPAD2/4, blk, 0, stream>>>(z, l1w + i*D_, l1b + i*D_, hb);
    wconv_k<<<dim3(3*D_/32, D_/32), wblk, 0, stream>>>(qkvw + (size_t)i*D_*3*D_, wb, D_, 3*D_);
    gemm256_k<0><<<9*MT2, blk5, 0, stream>>>(hb, wb, qkvb + i*3*D_, nullptr, qm, D_, 3*D_, 9);
    attn_k<<<MREAL/4, blk, 0, stream>>>(qm, hb);
    wconv_k<<<dim3(D_/32, D_/32), wblk, 0, stream>>>(topw + (size_t)i*D_*D_, wb, D_, D_);
    gemm256_k<1><<<3*MT2, blk5, 0, stream>>>(hb, wb, topb + i*D_, z, z, D_, D_, 3);
    ln_k<<<MPAD2/4, blk, 0, stream>>>(z, l2w + i*D_, l2b + i*D_, hb);
    wconv_k<<<dim3(DM_/32, D_/32), wblk, 0, stream>>>(w1 + (size_t)i*D_*DM_, wb, D_, DM_);
    gemm256_k<2><<<12*MT2, blk5, 0, stream>>>(hb, wb, b1 + i*DM_, nullptr, qm, D_, DM_, 12);
    wconv_k<<<dim3(D_/32, DM_/32), wblk, 0, stream>>>(w2 + (size_t)i*DM_*D_, wb, DM_, D_);
    gemm256_k<3><<<3*MT2, blk5, 0, stream>>>(qm, wb, b2 + i*D_, z, z, DM_, D_, 3);
  }

  // Head: LN(cls) -> MLP with gelu after both linears (small M -> 128^2 kernel)
  lncls_k<<<32, blk, 0, stream>>>(z, l3w, l3b, yb);
  wconv_k<<<dim3(DM_/32, D_/32), wblk, 0, stream>>>(hw1, wb, D_, DM_);
  gemm_k<2><<<24, blk, 0, stream>>>(yb, wb, hb1, nullptr, t1, D_, DM_, 24, 0, 0);
  wconv_k<<<dim3(1024/32, DM_/32), wblk, 0, stream>>>(hw2, wb, DM_, NC_);
  gemm_k<5><<<8, blk, 0, stream>>>(t1, wb, hb2, nullptr, (float*)d_out, DM_, 1024, 8, B_, NC_);
}

// Round 5
// 11239.779 us; speedup vs baseline: 1.4812x; 1.0544x over previous
//
#include <hip/hip_runtime.h>

typedef unsigned short u16;
typedef unsigned int u32;
typedef __bf16 bf16x8 __attribute__((ext_vector_type(8)));
typedef float f32x4 __attribute__((ext_vector_type(4)));

#define D_    768
#define DM_   3072
#define NL_   12
#define NT_   577
#define NP_   576
#define B_    64
#define MREAL (B_*NT_)      /* 36928 */
#define MPAD2 37120         /* 145*256 */
#define NC_   1000
#define IMG_  384

__device__ __forceinline__ float bf2f(u16 v){
  union { unsigned u; float f; } c; c.u = ((unsigned)v) << 16; return c.f;
}
__device__ __forceinline__ u16 f2bf(float f){
  union { float f; unsigned u; } c; c.f = f;
  unsigned r = c.u + 0x7FFFu + ((c.u >> 16) & 1u);
  return (u16)(r >> 16);
}
__device__ __forceinline__ float gelu_f(float x){
  return 0.5f * x * (1.0f + erff(x * 0.70710678118654752f));
}
__device__ __forceinline__ void gload16(const void* g, void* l){
  __builtin_amdgcn_global_load_lds((const __attribute__((address_space(1))) void*)g,
                                   (__attribute__((address_space(3))) void*)l, 16, 0, 0);
}

#define SB_ __builtin_amdgcn_sched_barrier(0)

// ---------------------------------------------------------------------------
// 256x256 GEMM, BK=64, 8 waves (2Mx4N), phase-split schedule (T3+T4+T5):
// per K-tile: [issue S0(t+1); vmcnt(2); barrier] then 4 phases
//   {ds_read 4-8 b128; issue stage pair; lgkmcnt(0); setprio(1); 16 MFMA;
//    setprio(0); barrier}
// Counted vmcnt never drains mid-loop (per-wave: 8 loads/tile, S0 in flight).
// Buffer epochs identical to the round-4 validated skeleton.
// EPI: 0=bf16 bias, 1=f32 bias+res, 2=bf16 gelu(bias), 3=f32 gelu(bias)+res,
//      4=f32 bias
// ---------------------------------------------------------------------------
template<int EPI>
__global__ __launch_bounds__(512, 1) void gemm256_k(
    const u16* __restrict__ A, const u16* __restrict__ Bt,
    const float* __restrict__ bias, const float* __restrict__ res,
    void* __restrict__ outv, int K, int ldo, int nbn)
{
  __shared__ u16 lds[2][2][256*64];
  const int tid = threadIdx.x;
  const int l   = tid & 63;
  const int wid = tid >> 6;
  const int wm  = wid >> 2, wn = wid & 3;
  const int lrow = l & 15;

  // bijective XCD swizzle (m204), bn-fastest
  const int nwg = gridDim.x;
  const int q = nwg >> 3, r = nwg & 7;
  const int xcd = blockIdx.x & 7, o = blockIdx.x >> 3;
  const int wg = (xcd < r ? xcd * (q + 1) : r * (q + 1) + (xcd - r) * q) + o;
  const int bm = wg / nbn, bn = wg % nbn;

  // staging: c = tid + 512*i -> row = c>>3 (0..255), col8 = c&7; src pre-swizzle
  const int cs8 = ((tid & 7) ^ ((tid >> 3) & 7)) * 8;
  const int rb  = tid >> 3;                       // 0..63
  const u16* aP[4]; const u16* bP[4];
  #pragma unroll
  for (int i = 0; i < 4; i++) {
    aP[i] = A  + (size_t)(bm*256 + rb + 64*i) * K + cs8;
    bP[i] = Bt + (size_t)(bn*256 + rb + 64*i) * K + cs8;
  }
  const int ldst = tid * 8;

  f32x4 acc[8][4];
  #pragma unroll
  for (int i = 0; i < 8; i++)
    #pragma unroll
    for (int j = 0; j < 4; j++) acc[i][j] = {0.f, 0.f, 0.f, 0.f};

  const int nk = K >> 6;
  // prologue: stage tile 0 -> dbuf 0 (8 loads/wave)
  #pragma unroll
  for (int i = 0; i < 4; i++) {
    gload16(aP[i], &lds[0][0][ldst + i*4096]);
    gload16(bP[i], &lds[0][1][ldst + i*4096]);
    aP[i] += 64; bP[i] += 64;
  }

  const int sw  = (lrow & 7) << 4;
  const int g16 = (l >> 4) << 4;

  for (int t = 0; t < nk; ++t) {
    const int cur = t & 1;
    const bool pre = (t + 1 < nk);
    u16* dA = &lds[cur^1][0][0];
    u16* dB = &lds[cur^1][1][0];

    // issue S0(t+1) = A quarters 0,1; then counted wait for tile t
    if (pre) {
      gload16(aP[0], dA + ldst);
      gload16(aP[1], dA + ldst + 4096);
    }
    SB_;
    if (pre) asm volatile("s_waitcnt vmcnt(2)" ::: "memory");
    else     asm volatile("s_waitcnt vmcnt(0)" ::: "memory");
    SB_;
    __builtin_amdgcn_s_barrier();
    SB_;

    const char* As_ = (const char*)&lds[cur][0][0];
    const char* Bs_ = (const char*)&lds[cur][1][0];
    bf16x8 af[4], bfr[4];

    // ---- phase 0: kk=0, B + A[0..3]; stage S1 (A quarters 2,3)
    {
      const int kb = g16;
      #pragma unroll
      for (int ni = 0; ni < 4; ni++)
        bfr[ni] = *(const bf16x8*)(Bs_ + ((wn*64 + ni*16 + lrow) << 7) + (kb ^ sw));
      #pragma unroll
      for (int mi = 0; mi < 4; mi++)
        af[mi] = *(const bf16x8*)(As_ + ((wm*128 + mi*16 + lrow) << 7) + (kb ^ sw));
      if (pre) {
        gload16(aP[2], dA + ldst + 8192);
        gload16(aP[3], dA + ldst + 12288);
      }
      asm volatile("s_waitcnt lgkmcnt(0)" ::: "memory");
      SB_;
      __builtin_amdgcn_s_setprio(1);
      #pragma unroll
      for (int mi = 0; mi < 4; mi++)
        #pragma unroll
        for (int ni = 0; ni < 4; ni++)
          acc[mi][ni] = __builtin_amdgcn_mfma_f32_16x16x32_bf16(af[mi], bfr[ni], acc[mi][ni], 0, 0, 0);
      __builtin_amdgcn_s_setprio(0);
      SB_;
      __builtin_amdgcn_s_barrier();
      SB_;
    }
    // ---- phase 1: kk=0, A[4..7] (B reused); stage S2 (B quarters 0,1)
    {
      const int kb = g16;
      #pragma unroll
      for (int mi = 0; mi < 4; mi++)
        af[mi] = *(const bf16x8*)(As_ + ((wm*128 + (mi+4)*16 + lrow) << 7) + (kb ^ sw));
      if (pre) {
        gload16(bP[0], dB + ldst);
        gload16(bP[1], dB + ldst + 4096);
      }
      asm volatile("s_waitcnt lgkmcnt(0)" ::: "memory");
      SB_;
      __builtin_amdgcn_s_setprio(1);
      #pragma unroll
      for (int mi = 0; mi < 4; mi++)
        #pragma unroll
        for (int ni = 0; ni < 4; ni++)
          acc[mi+4][ni] = __builtin_amdgcn_mfma_f32_16x16x32_bf16(af[mi], bfr[ni], acc[mi+4][ni], 0, 0, 0);
      __builtin_amdgcn_s_setprio(0);
      SB_;
      __builtin_amdgcn_s_barrier();
      SB_;
    }
    // ---- phase 2: kk=1, B + A[0..3]; stage S3 (B quarters 2,3)
    {
      const int kb = 64 | g16;
      #pragma unroll
      for (int ni = 0; ni < 4; ni++)
        bfr[ni] = *(const bf16x8*)(Bs_ + ((wn*64 + ni*16 + lrow) << 7) + (kb ^ sw));
      #pragma unroll
      for (int mi = 0; mi < 4; mi++)
        af[mi] = *(const bf16x8*)(As_ + ((wm*128 + mi*16 + lrow) << 7) + (kb ^ sw));
      if (pre) {
        gload16(bP[2], dB + ldst + 8192);
        gload16(bP[3], dB + ldst + 12288);
      }
      asm volatile("s_waitcnt lgkmcnt(0)" ::: "memory");
      SB_;
      __builtin_amdgcn_s_setprio(1);
      #pragma unroll
      for (int mi = 0; mi < 4; mi++)
        #pragma unroll
        for (int ni = 0; ni < 4; ni++)
          acc[mi][ni] = __builtin_amdgcn_mfma_f32_16x16x32_bf16(af[mi], bfr[ni], acc[mi][ni], 0, 0, 0);
      __builtin_amdgcn_s_setprio(0);
      SB_;
      __builtin_amdgcn_s_barrier();
      SB_;
    }
    // ---- phase 3: kk=1, A[4..7]; no stage
    {
      const int kb = 64 | g16;
      #pragma unroll
      for (int mi = 0; mi < 4; mi++)
        af[mi] = *(const bf16x8*)(As_ + ((wm*128 + (mi+4)*16 + lrow) << 7) + (kb ^ sw));
      asm volatile("s_waitcnt lgkmcnt(0)" ::: "memory");
      SB_;
      __builtin_amdgcn_s_setprio(1);
      #pragma unroll
      for (int mi = 0; mi < 4; mi++)
        #pragma unroll
        for (int ni = 0; ni < 4; ni++)
          acc[mi+4][ni] = __builtin_amdgcn_mfma_f32_16x16x32_bf16(af[mi], bfr[ni], acc[mi+4][ni], 0, 0, 0);
      __builtin_amdgcn_s_setprio(0);
      SB_;
      __builtin_amdgcn_s_barrier();
      SB_;
    }
    if (pre) {
      #pragma unroll
      for (int i = 0; i < 4; i++) { aP[i] += 64; bP[i] += 64; }
    }
  }

  const int orow0 = bm*256 + wm*128;
  const int ocol0 = bn*256 + wn*64;
  #pragma unroll
  for (int mi = 0; mi < 8; mi++) {
    #pragma unroll
    for (int ni = 0; ni < 4; ni++) {
      const int col = ocol0 + ni*16 + (l & 15);
      const float bv = bias[col];
      #pragma unroll
      for (int r2 = 0; r2 < 4; r2++) {
        const int row = orow0 + mi*16 + (l >> 4)*4 + r2;
        const float v = acc[mi][ni][r2] + bv;
        const size_t idx = (size_t)row * ldo + col;
        if constexpr (EPI == 0) ((u16*)outv)[idx] = f2bf(v);
        else if constexpr (EPI == 1) ((float*)outv)[idx] = v + res[idx];
        else if constexpr (EPI == 2) ((u16*)outv)[idx] = f2bf(gelu_f(v));
        else if constexpr (EPI == 3) ((float*)outv)[idx] = gelu_f(v) + res[idx];
        else if constexpr (EPI == 4) ((float*)outv)[idx] = v;
      }
    }
  }
}

// ---------------------------------------------------------------------------
// 128x128 single-buffered GEMM — kept for small head GEMMs.
// EPI: 2=bf16 gelu(bias), 5=f32 gelu(bias) bounded store [Ms,Ns]
// ---------------------------------------------------------------------------
template<int EPI>
__global__ __launch_bounds__(256) void gemm_k(
    const u16* __restrict__ A, const u16* __restrict__ Bt,
    const float* __restrict__ bias, const float* __restrict__ res,
    void* __restrict__ outv, int K, int ldo, int nbn, int Ms, int Ns)
{
  __shared__ u16 As[128*64];
  __shared__ u16 Bs[128*64];
  const int tid = threadIdx.x;
  const int l   = tid & 63;
  const int w   = tid >> 6;
  const int wm  = w >> 1, wn = w & 1;
  const int lrow = l & 15;

  const int nwg = gridDim.x;
  const int q = nwg >> 3, r = nwg & 7;
  const int xcd = blockIdx.x & 7, o = blockIdx.x >> 3;
  const int wg = (xcd < r ? xcd * (q + 1) : r * (q + 1) + (xcd - r) * q) + o;
  const int bm = wg / nbn, bn = wg % nbn;

  const int cs8 = ((tid & 7) ^ ((tid >> 3) & 7)) * 8;
  const int rb  = tid >> 3;
  const size_t abase = (size_t)bm * 128 * K;
  const size_t bbase = (size_t)bn * 128 * K;
  size_t aoff[4], boff[4];
  #pragma unroll
  for (int i = 0; i < 4; i++) {
    aoff[i] = abase + (size_t)(rb + 32 * i) * K + cs8;
    boff[i] = bbase + (size_t)(rb + 32 * i) * K + cs8;
  }

  const int colA = (l >> 4) << 4;
  const int sw   = (lrow & 7) << 4;

  f32x4 acc[4][4];
  #pragma unroll
  for (int i = 0; i < 4; i++)
    #pragma unroll
    for (int j = 0; j < 4; j++) acc[i][j] = {0.f, 0.f, 0.f, 0.f};

  const int nk = K >> 6;
  for (int kt = 0; kt < nk; ++kt) {
    const int koff = kt * 64;
    #pragma unroll
    for (int i = 0; i < 4; i++) {
      gload16(A  + aoff[i] + koff, As + tid * 8 + i * 2048);
      gload16(Bt + boff[i] + koff, Bs + tid * 8 + i * 2048);
    }
    __syncthreads();
    #pragma unroll
    for (int kk = 0; kk < 2; kk++) {
      bf16x8 af[4], bfr[4];
      #pragma unroll
      for (int mi = 0; mi < 4; mi++)
        af[mi] = *(const bf16x8*)((const char*)As +
                  ((wm*64 + mi*16 + lrow) << 7) + (((kk << 6) | colA) ^ sw));
      #pragma unroll
      for (int ni = 0; ni < 4; ni++)
        bfr[ni] = *(const bf16x8*)((const char*)Bs +
                  ((wn*64 + ni*16 + lrow) << 7) + (((kk << 6) | colA) ^ sw));
      #pragma unroll
      for (int mi = 0; mi < 4; mi++)
        #pragma unroll
        for (int ni = 0; ni < 4; ni++)
          acc[mi][ni] = __builtin_amdgcn_mfma_f32_16x16x32_bf16(af[mi], bfr[ni], acc[mi][ni], 0, 0, 0);
    }
    __syncthreads();
  }

  const int orow0 = bm*128 + wm*64;
  const int ocol0 = bn*128 + wn*64;
  #pragma unroll
  for (int mi = 0; mi < 4; mi++) {
    #pragma unroll
    for (int ni = 0; ni < 4; ni++) {
      #pragma unroll
      for (int r2 = 0; r2 < 4; r2++) {
        const int row = orow0 + mi*16 + (l >> 4)*4 + r2;
        const int col = ocol0 + ni*16 + (l & 15);
        float bv;
        if constexpr (EPI == 5) bv = (col < Ns) ? bias[col] : 0.f;
        else bv = bias[col];
        const float v = acc[mi][ni][r2] + bv;
        const size_t idx = (size_t)row * ldo + col;
        if constexpr (EPI == 2) ((u16*)outv)[idx] = f2bf(gelu_f(v));
        else if constexpr (EPI == 5) {
          if (row < Ms && col < Ns) ((float*)outv)[(size_t)row * Ns + col] = gelu_f(v);
        }
      }
    }
  }
}

// ---------------------------------------------------------------------------
__global__ void wconv_k(const float* __restrict__ W, u16* __restrict__ Wt,
                        int K, int N)
{
  __shared__ float tile[32][33];
  const int n0 = blockIdx.x * 32, k0 = blockIdx.y * 32;
  const int tx = threadIdx.x, ty = threadIdx.y;
  #pragma unroll
  for (int r = 0; r < 4; r++) {
    const int kk = k0 + ty + r*8;
    const int nn = n0 + tx;
    tile[ty + r*8][tx] = (nn < N) ? W[(size_t)kk * N + nn] : 0.f;
  }
  __syncthreads();
  #pragma unroll
  for (int r = 0; r < 4; r++) {
    const int nn = n0 + ty + r*8;
    Wt[(size_t)nn * K + k0 + tx] = f2bf(tile[tx][ty + r*8]);
  }
}

// ---------------------------------------------------------------------------
__global__ void patchify_k(const float* __restrict__ x, u16* __restrict__ hb)
{
  const int blk = blockIdx.x;
  const int b = blk / NP_, p = blk % NP_;
  const int pr = p / 24, pc = p % 24;
  const size_t row = (size_t)b * NT_ + 1 + p;
  #pragma unroll
  for (int u = 0; u < 3; u++) {
    const int j  = threadIdx.x + u * 256;
    const int c  = j >> 8, ph = (j >> 4) & 15, pw = j & 15;
    const float v = x[((size_t)(b*3 + c) * IMG_ + pr*16 + ph) * IMG_ + pc*16 + pw];
    hb[row * D_ + j] = f2bf(v);
  }
}

__global__ void posecls_k(float* __restrict__ z, const float* __restrict__ ce,
                          const float* __restrict__ pe)
{
  const int row = blockIdx.x;
  const int t = row % NT_;
  const size_t base = (size_t)row * D_;
  #pragma unroll
  for (int u = 0; u < 3; u++) {
    const int j = threadIdx.x + u * 256;
    if (t == 0) z[base + j] = ce[j] + pe[j];
    else        z[base + j] += pe[(size_t)t * D_ + j];
  }
}

// LayerNorm: one wave per row, float4 loads, f32 in -> bf16 out
__global__ void ln_k(const float* __restrict__ z, const float* __restrict__ w,
                     const float* __restrict__ b, u16* __restrict__ out)
{
  const int row = blockIdx.x * 4 + (threadIdx.x >> 6);
  const int l = threadIdx.x & 63;
  const float4* zr = (const float4*)(z + (size_t)row * D_);
  float4 xq[3];
  float s = 0.f;
  #pragma unroll
  for (int j = 0; j < 3; j++) {
    xq[j] = zr[j*64 + l];
    s += xq[j].x + xq[j].y + xq[j].z + xq[j].w;
  }
  #pragma unroll
  for (int m = 1; m < 64; m <<= 1) s += __shfl_xor(s, m, 64);
  const float mean = s * (1.0f / 768.0f);
  float ss = 0.f;
  #pragma unroll
  for (int j = 0; j < 3; j++) {
    const float dx = xq[j].x-mean, dy = xq[j].y-mean, dz = xq[j].z-mean, dw = xq[j].w-mean;
    ss += dx*dx + dy*dy + dz*dz + dw*dw;
  }
  #pragma unroll
  for (int m = 1; m < 64; m <<= 1) ss += __shfl_xor(ss, m, 64);
  const float rinv = rsqrtf(ss * (1.0f / 768.0f) + 1e-5f);
  const size_t ob = (size_t)row * D_;
  #pragma unroll
  for (int j = 0; j < 3; j++) {
    const int c = (j*64 + l) * 4;
    const float4 wv = *(const float4*)(w + c);
    const float4 bv = *(const float4*)(b + c);
    ushort4 ov;
    ov.x = f2bf((xq[j].x - mean) * rinv * wv.x + bv.x);
    ov.y = f2bf((xq[j].y - mean) * rinv * wv.y + bv.y);
    ov.z = f2bf((xq[j].z - mean) * rinv * wv.z + bv.z);
    ov.w = f2bf((xq[j].w - mean) * rinv * wv.w + bv.w);
    *(ushort4*)(out + ob + c) = ov;
  }
}

// Final LN over cls rows -> yb[128][768] bf16 (rows >= 64 zeroed)
__global__ void lncls_k(const float* __restrict__ z, const float* __restrict__ w,
                        const float* __restrict__ b, u16* __restrict__ out)
{
  const int row = blockIdx.x * 4 + (threadIdx.x >> 6);   // 0..127
  const int l = threadIdx.x & 63;
  const size_t ob = (size_t)row * D_;
  if (row >= B_) {
    #pragma unroll
    for (int j = 0; j < 12; j++) out[ob + j*64 + l] = 0;
    return;
  }
  const float* zr = z + (size_t)row * NT_ * D_;
  float xv[12];
  float s = 0.f;
  #pragma unroll
  for (int j = 0; j < 12; j++) { xv[j] = zr[j*64 + l]; s += xv[j]; }
  #pragma unroll
  for (int m = 1; m < 64; m <<= 1) s += __shfl_xor(s, m, 64);
  const float mean = s * (1.0f / 768.0f);
  float ss = 0.f;
  #pragma unroll
  for (int j = 0; j < 12; j++) { const float d = xv[j] - mean; ss += d * d; }
  #pragma unroll
  for (int m = 1; m < 64; m <<= 1) ss += __shfl_xor(ss, m, 64);
  const float rinv = rsqrtf(ss * (1.0f / 768.0f) + 1e-5f);
  #pragma unroll
  for (int j = 0; j < 12; j++) {
    const int cidx = j*64 + l;
    out[ob + cidx] = f2bf((xv[j] - mean) * rinv * w[cidx] + b[cidx]);
  }
}

// ---------------------------------------------------------------------------
// MFMA per-token head-axis attention (round-3 proven).
// ---------------------------------------------------------------------------
__global__ __launch_bounds__(256) void attn_k(const u16* __restrict__ qkv,
                                              u16* __restrict__ o)
{
  const int tok = (blockIdx.x * 256 + threadIdx.x) >> 6;
  const int l  = threadIdx.x & 63;
  const int g  = l >> 4, li = l & 15;
  const size_t rb = (size_t)tok * (3 * D_);

  f32x4 s = {0.f, 0.f, 0.f, 0.f};
  #pragma unroll
  for (int kt = 0; kt < 2; kt++) {
    const bf16x8 ka = *(const bf16x8*)(qkv + rb + D_ + li*64 + g*8 + kt*32);
    const bf16x8 qb = *(const bf16x8*)(qkv + rb +      li*64 + g*8 + kt*32);
    s = __builtin_amdgcn_mfma_f32_16x16x32_bf16(ka, qb, s, 0, 0, 0);
  }

  float sv[4];
  #pragma unroll
  for (int r2 = 0; r2 < 4; r2++) sv[r2] = s[r2] * 0.125f;
  float mx = (g < 3) ? fmaxf(fmaxf(sv[0], sv[1]), fmaxf(sv[2], sv[3])) : -1e30f;
  mx = fmaxf(mx, __shfl_xor(mx, 16, 64));
  mx = fmaxf(mx, __shfl_xor(mx, 32, 64));
  float p[4], den = 0.f;
  #pragma unroll
  for (int r2 = 0; r2 < 4; r2++) {
    p[r2] = (g < 3) ? __expf(sv[r2] - mx) : 0.f;
    den += p[r2];
  }
  den += __shfl_xor(den, 16, 64);
  den += __shfl_xor(den, 32, 64);
  const float rden = 1.0f / den;
  #pragma unroll
  for (int r2 = 0; r2 < 4; r2++) p[r2] *= rden;

  const u32 pk01 = ((u32)f2bf(p[1]) << 16) | f2bf(p[0]);
  const u32 pk23 = ((u32)f2bf(p[3]) << 16) | f2bf(p[2]);

  const int srcA = (li + (g << 5)) & 63;
  const int srcB = (srcA + 16) & 63;
  u32 b0 = (u32)__shfl((int)pk01, srcA, 64);
  u32 b1 = (u32)__shfl((int)pk23, srcA, 64);
  u32 b2 = (u32)__shfl((int)pk01, srcB, 64);
  u32 b3 = (u32)__shfl((int)pk23, srcB, 64);
  if (g >= 2) { b0 = 0; b1 = 0; b2 = 0; b3 = 0; }
  union { u32 u[4]; bf16x8 v; } pb;
  pb.u[0] = b0; pb.u[1] = b1; pb.u[2] = b2; pb.u[3] = b3;

  const size_t ob = (size_t)tok * D_;
  #pragma unroll
  for (int t = 0; t < 4; t++) {
    union { u16 a[8]; bf16x8 v; } va;
    #pragma unroll
    for (int jp = 0; jp < 8; jp++) {
      const int j = g * 8 + jp;
      va.a[jp] = (j < 12) ? qkv[rb + 2*D_ + j*64 + t*16 + li] : (u16)0;
    }
    f32x4 oac = {0.f, 0.f, 0.f, 0.f};
    oac = __builtin_amdgcn_mfma_f32_16x16x32_bf16(va.v, pb.v, oac, 0, 0, 0);
    if (li < 12) {
      ushort4 ov;
      ov.x = f2bf(oac[0]); ov.y = f2bf(oac[1]);
      ov.z = f2bf(oac[2]); ov.w = f2bf(oac[3]);
      *(ushort4*)(o + ob + li*64 + t*16 + g*4) = ov;
    }
  }
}

// ---------------------------------------------------------------------------
extern "C" void kernel_launch(void* const* d_in, const int* in_sizes, int n_in,
                              void* d_out, int out_size, void* d_ws, size_t ws_size,
                              hipStream_t stream)
{
  const float* x    = (const float*)d_in[0];
  const float* ce   = (const float*)d_in[1];
  const float* pe   = (const float*)d_in[2];
  const float* pw   = (const float*)d_in[3];
  const float* pb   = (const float*)d_in[4];
  const float* qkvw = (const float*)d_in[5];
  const float* qkvb = (const float*)d_in[6];
  const float* topw = (const float*)d_in[7];
  const float* topb = (const float*)d_in[8];
  const float* l1w  = (const float*)d_in[9];
  const float* l1b  = (const float*)d_in[10];
  const float* l2w  = (const float*)d_in[11];
  const float* l2b  = (const float*)d_in[12];
  const float* w1   = (const float*)d_in[13];
  const float* b1   = (const float*)d_in[14];
  const float* w2   = (const float*)d_in[15];
  const float* b2   = (const float*)d_in[16];
  const float* l3w  = (const float*)d_in[17];
  const float* l3b  = (const float*)d_in[18];
  const float* hw1  = (const float*)d_in[19];
  const float* hb1  = (const float*)d_in[20];
  const float* hw2  = (const float*)d_in[21];
  const float* hb2  = (const float*)d_in[22];

  char* ws = (char*)d_ws;
  constexpr size_t SZ_Z  = (size_t)MPAD2 * D_ * 4;
  constexpr size_t SZ_HB = (size_t)MPAD2 * D_ * 2;
  constexpr size_t SZ_QM = (size_t)MPAD2 * DM_ * 2;
  constexpr size_t SZ_WB = (size_t)DM_ * 1024 * 2;
  constexpr size_t SZ_YB = (size_t)128 * D_ * 2;
  float* z  = (float*)ws;
  u16*   hb = (u16*)(ws + SZ_Z);
  u16*   qm = (u16*)(ws + SZ_Z + SZ_HB);
  u16*   wb = (u16*)(ws + SZ_Z + SZ_HB + SZ_QM);
  u16*   yb = (u16*)(ws + SZ_Z + SZ_HB + SZ_QM + SZ_WB);
  u16*   t1 = (u16*)(ws + SZ_Z + SZ_HB + SZ_QM + SZ_WB + SZ_YB);

  const dim3 blk(256);
  const dim3 blk5(512);
  const dim3 wblk(32, 8);
  const int MT2 = MPAD2 / 256;  // 145

  // Patch embedding
  patchify_k<<<B_ * NP_, blk, 0, stream>>>(x, hb);
  wconv_k<<<dim3(D_/32, D_/32), wblk, 0, stream>>>(pw, wb, D_, D_);
  gemm256_k<4><<<3*MT2, blk5, 0, stream>>>(hb, wb, pb, nullptr, z, D_, D_, 3);
  posecls_k<<<MREAL, blk, 0, stream>>>(z, ce, pe);

  for (int i = 0; i < NL_; i++) {
    ln_k<<<MPAD2/4, blk, 0, stream>>>(z, l1w + i*D_, l1b + i*D_, hb);
    wconv_k<<<dim3(3*D_/32, D_/32), wblk, 0, stream>>>(qkvw + (size_t)i*D_*3*D_, wb, D_, 3*D_);
    gemm256_k<0><<<9*MT2, blk5, 0, stream>>>(hb, wb, qkvb + i*3*D_, nullptr, qm, D_, 3*D_, 9);
    attn_k<<<MREAL/4, blk, 0, stream>>>(qm, hb);
    wconv_k<<<dim3(D_/32, D_/32), wblk, 0, stream>>>(topw + (size_t)i*D_*D_, wb, D_, D_);
    gemm256_k<1><<<3*MT2, blk5, 0, stream>>>(hb, wb, topb + i*D_, z, z, D_, D_, 3);
    ln_k<<<MPAD2/4, blk, 0, stream>>>(z, l2w + i*D_, l2b + i*D_, hb);
    wconv_k<<<dim3(DM_/32, D_/32), wblk, 0, stream>>>(w1 + (size_t)i*D_*DM_, wb, D_, DM_);
    gemm256_k<2><<<12*MT2, blk5, 0, stream>>>(hb, wb, b1 + i*DM_, nullptr, qm, D_, DM_, 12);
    wconv_k<<<dim3(D_/32, DM_/32), wblk, 0, stream>>>(w2 + (size_t)i*DM_*D_, wb, DM_, D_);
    gemm256_k<3><<<3*MT2, blk5, 0, stream>>>(qm, wb, b2 + i*D_, z, z, DM_, D_, 3);
  }

  // Head: LN(cls) -> MLP with gelu after both linears (small M -> 128^2 kernel)
  lncls_k<<<32, blk, 0, stream>>>(z, l3w, l3b, yb);
  wconv_k<<<dim3(DM_/32, D_/32), wblk, 0, stream>>>(hw1, wb, D_, DM_);
  gemm_k<2><<<24, blk, 0, stream>>>(yb, wb, hb1, nullptr, t1, D_, DM_, 24, 0, 0);
  wconv_k<<<dim3(1024/32, DM_/32), wblk, 0, stream>>>(hw2, wb, DM_, NC_);
  gemm_k<5><<<8, blk, 0, stream>>>(t1, wb, hb2, nullptr, (float*)d_out, DM_, 1024, 8, B_, NC_);
}